// Round 1
// baseline (17639.078 us; speedup 1.0000x reference)
//
#include <hip/hip_runtime.h>
#include <math.h>

#define N_NODES 100000
#define N_EDGES 1600000
#define DIN 256

// ---------------- degree ----------------
__global__ void deg_kernel(const int* __restrict__ dst, float* __restrict__ deg) {
    long long stride = (long long)gridDim.x * blockDim.x;
    for (long long e = (long long)blockIdx.x * blockDim.x + threadIdx.x; e < N_EDGES; e += stride) {
        atomicAdd(&deg[dst[e]], 1.0f);
    }
}

__global__ void rinv_kernel(float* __restrict__ deg) {
    int i = blockIdx.x * blockDim.x + threadIdx.x;
    if (i < N_NODES) deg[i] = 1.0f / fmaxf(deg[i], 1.0f);
}

// ---------------- scatter-add aggregation ----------------
// one virtual thread per (edge, 4-float chunk): 64 chunks of 4 floats = 256 feats
__global__ void scatter_kernel(const int* __restrict__ src, const int* __restrict__ dst,
                               const float* __restrict__ h, float* __restrict__ agg) {
    const long long total = (long long)N_EDGES * 64;
    const long long stride = (long long)gridDim.x * blockDim.x;
    for (long long tid = (long long)blockIdx.x * blockDim.x + threadIdx.x; tid < total; tid += stride) {
        int e = (int)(tid >> 6);
        int c = ((int)tid & 63) << 2;
        int s = src[e];
        int d = dst[e];
        const float4 v = *(const float4*)(h + (size_t)s * DIN + c);
        float* p = agg + (size_t)d * DIN + c;
        atomicAdd(p + 0, v.x);
        atomicAdd(p + 1, v.y);
        atomicAdd(p + 2, v.z);
        atomicAdd(p + 3, v.w);
    }
}

// ---------------- fused dual GEMM ----------------
// out[row, col] = act( sum_k (agg[row,k]*rinv[row])*Wl[col,k] + sum_k h[row,k]*Wr[col,k] + b[col] )
// Virtual K = 512: k<256 -> (agg*rinv, Wl); k>=256 -> (h, Wr).
#define BM 64
#define BN 64
#define BK 32

__launch_bounds__(256)
__global__ void sage_gemm(const float* __restrict__ Agg, const float* __restrict__ rinv,
                          const float* __restrict__ H,
                          const float* __restrict__ Wl, const float* __restrict__ Wr,
                          const float* __restrict__ bias, float* __restrict__ out,
                          int dout, int do_relu) {
    __shared__ float sA[BK][BM + 1];
    __shared__ float sB[BK][BN + 1];

    const int row0 = blockIdx.x * BM;
    const int col0 = blockIdx.y * BN;
    const int t  = threadIdx.x;
    const int tx = t & 15;
    const int ty = t >> 4;

    float acc[4][4] = {};

    for (int kt = 0; kt < 512; kt += BK) {
        // A tile: 64 rows x 32 k  (512 float4 loads, 2 per thread)
        #pragma unroll
        for (int i = 0; i < 2; ++i) {
            int idx = t + i * 256;       // 0..511
            int r   = idx >> 3;          // 0..63
            int kc  = (idx & 7) * 4;     // 0,4,...,28
            int row = row0 + r;
            int kk  = kt + kc;
            float4 v = make_float4(0.f, 0.f, 0.f, 0.f);
            if (row < N_NODES) {
                if (kk < 256) {
                    v = *(const float4*)(Agg + (size_t)row * DIN + kk);
                    float rs = rinv[row];
                    v.x *= rs; v.y *= rs; v.z *= rs; v.w *= rs;
                } else {
                    v = *(const float4*)(H + (size_t)row * DIN + (kk - 256));
                }
            }
            sA[kc + 0][r] = v.x; sA[kc + 1][r] = v.y;
            sA[kc + 2][r] = v.z; sA[kc + 3][r] = v.w;
        }
        // B tile: 64 cols x 32 k
        #pragma unroll
        for (int i = 0; i < 2; ++i) {
            int idx = t + i * 256;
            int c   = idx >> 3;
            int kc  = (idx & 7) * 4;
            int col = col0 + c;
            int kk  = kt + kc;
            float4 v;
            if (kk < 256) v = *(const float4*)(Wl + (size_t)col * DIN + kk);
            else          v = *(const float4*)(Wr + (size_t)col * DIN + (kk - 256));
            sB[kc + 0][c] = v.x; sB[kc + 1][c] = v.y;
            sB[kc + 2][c] = v.z; sB[kc + 3][c] = v.w;
        }
        __syncthreads();

        #pragma unroll
        for (int k = 0; k < BK; ++k) {
            float a[4], bb[4];
            #pragma unroll
            for (int i = 0; i < 4; ++i) a[i] = sA[k][ty * 4 + i];
            #pragma unroll
            for (int j = 0; j < 4; ++j) bb[j] = sB[k][tx * 4 + j];
            #pragma unroll
            for (int i = 0; i < 4; ++i)
                #pragma unroll
                for (int j = 0; j < 4; ++j)
                    acc[i][j] += a[i] * bb[j];
        }
        __syncthreads();
    }

    #pragma unroll
    for (int i = 0; i < 4; ++i) {
        int row = row0 + ty * 4 + i;
        if (row >= N_NODES) continue;
        #pragma unroll
        for (int j = 0; j < 4; ++j) {
            int col = col0 + tx * 4 + j;
            float v = acc[i][j] + bias[col];
            if (do_relu) v = fmaxf(v, 0.0f);
            out[(size_t)row * dout + col] = v;
        }
    }
}

// ---------------- classifier: sigmoid(h3 . Wc + bc) ----------------
__global__ void cls_kernel(const float* __restrict__ h3, const float* __restrict__ Wc,
                           const float* __restrict__ bc, float* __restrict__ out) {
    __shared__ float sW[128];
    int t = threadIdx.x;
    if (t < 128) sW[t] = Wc[t];
    __syncthreads();
    int row  = blockIdx.x * 8 + (t >> 5);   // 8 rows per 256-thread block
    int lane = t & 31;
    if (row >= N_NODES) return;
    float4 v = *(const float4*)(h3 + (size_t)row * 128 + lane * 4);
    float4 w = *(const float4*)(sW + lane * 4);
    float s = v.x * w.x + v.y * w.y + v.z * w.z + v.w * w.w;
    #pragma unroll
    for (int off = 16; off; off >>= 1) s += __shfl_xor(s, off, 32);
    if (lane == 0) {
        float z = s + bc[0];
        out[row] = 1.0f / (1.0f + expf(-z));
    }
}

extern "C" void kernel_launch(void* const* d_in, const int* in_sizes, int n_in,
                              void* d_out, int out_size, void* d_ws, size_t ws_size,
                              hipStream_t stream) {
    const float* x   = (const float*)d_in[0];
    const int*   ei  = (const int*)d_in[1];
    const float* Wl0 = (const float*)d_in[2];
    const float* Wr0 = (const float*)d_in[3];
    const float* b0  = (const float*)d_in[4];
    const float* Wl1 = (const float*)d_in[5];
    const float* Wr1 = (const float*)d_in[6];
    const float* b1  = (const float*)d_in[7];
    const float* Wl2 = (const float*)d_in[8];
    const float* Wr2 = (const float*)d_in[9];
    const float* b2  = (const float*)d_in[10];
    const float* Wc  = (const float*)d_in[11];
    const float* bc  = (const float*)d_in[12];
    float* out = (float*)d_out;

    const int* src = ei;             // edge_index[0]
    const int* dst = ei + N_EDGES;   // edge_index[1]

    // workspace layout (floats)
    float* ws   = (float*)d_ws;
    float* deg  = ws;                          // N
    float* bufA = ws + 100352;                 // agg: N*256
    float* bufB = bufA + (size_t)N_NODES * 256; // h1 / h3
    float* bufC = bufB + (size_t)N_NODES * 256; // h2

    const size_t aggBytes = (size_t)N_NODES * 256 * sizeof(float);

    // degree (once; graph is fixed across layers)
    hipMemsetAsync(deg, 0, N_NODES * sizeof(float), stream);
    deg_kernel<<<2048, 256, 0, stream>>>(dst, deg);
    rinv_kernel<<<(N_NODES + 255) / 256, 256, 0, stream>>>(deg);

    dim3 gemm_grid((N_NODES + BM - 1) / BM, 4);
    dim3 gemm_grid2((N_NODES + BM - 1) / BM, 2);

    // ---- layer 0 ----
    hipMemsetAsync(bufA, 0, aggBytes, stream);
    scatter_kernel<<<4096, 256, 0, stream>>>(src, dst, x, bufA);
    sage_gemm<<<gemm_grid, 256, 0, stream>>>(bufA, deg, x, Wl0, Wr0, b0, bufB, 256, 1);

    // ---- layer 1 ----
    hipMemsetAsync(bufA, 0, aggBytes, stream);
    scatter_kernel<<<4096, 256, 0, stream>>>(src, dst, bufB, bufA);
    sage_gemm<<<gemm_grid, 256, 0, stream>>>(bufA, deg, bufB, Wl1, Wr1, b1, bufC, 256, 1);

    // ---- layer 2 (no relu), output 128-dim into bufB ----
    hipMemsetAsync(bufA, 0, aggBytes, stream);
    scatter_kernel<<<4096, 256, 0, stream>>>(src, dst, bufC, bufA);
    sage_gemm<<<gemm_grid2, 256, 0, stream>>>(bufA, deg, bufC, Wl2, Wr2, b2, bufB, 128, 0);

    // ---- classifier ----
    cls_kernel<<<(N_NODES + 7) / 8, 256, 0, stream>>>(bufB, Wc, bc, out);
}

// Round 2
// 2294.839 us; speedup vs baseline: 7.6864x; 7.6864x over previous
//
#include <hip/hip_runtime.h>
#include <math.h>

#define N_NODES 100000
#define N_PAD   100352   // N rounded up to multiple of 256
#define N_EDGES 1600000
#define DIN 256

// ---------------- CSR build ----------------
__global__ void hist_kernel(const int* __restrict__ dst, int* __restrict__ cnt) {
    long long stride = (long long)gridDim.x * blockDim.x;
    for (long long e = (long long)blockIdx.x * blockDim.x + threadIdx.x; e < N_EDGES; e += stride)
        atomicAdd(&cnt[dst[e]], 1);
}

__global__ void scan1_kernel(const int* __restrict__ cnt, int* __restrict__ excl,
                             int* __restrict__ blocksums) {
    __shared__ int s[256];
    int tid = threadIdx.x;
    int i = blockIdx.x * 256 + tid;
    int v = (i < N_NODES) ? cnt[i] : 0;
    s[tid] = v;
    __syncthreads();
    for (int off = 1; off < 256; off <<= 1) {
        int t = (tid >= off) ? s[tid - off] : 0;
        __syncthreads();
        s[tid] += t;
        __syncthreads();
    }
    if (i < N_NODES) excl[i] = s[tid] - v;
    if (tid == 255) blocksums[blockIdx.x] = s[255];
}

__global__ void scan2_kernel(int* __restrict__ blocksums, int nb) {
    __shared__ int s[512];
    int tid = threadIdx.x;
    int v = (tid < nb) ? blocksums[tid] : 0;
    s[tid] = v;
    __syncthreads();
    for (int off = 1; off < 512; off <<= 1) {
        int t = (tid >= off) ? s[tid - off] : 0;
        __syncthreads();
        s[tid] += t;
        __syncthreads();
    }
    if (tid < nb) blocksums[tid] = s[tid] - v;   // exclusive
}

__global__ void scan3_kernel(int* __restrict__ excl, const int* __restrict__ blocksums) {
    int i = blockIdx.x * 256 + threadIdx.x;
    if (i < N_NODES) excl[i] += blocksums[blockIdx.x];
}

__global__ void rinv_copy_kernel(const int* __restrict__ cnt, float* __restrict__ rinv,
                                 const int* __restrict__ rowptr, int* __restrict__ cursor) {
    int i = blockIdx.x * 256 + threadIdx.x;
    if (i < N_NODES) {
        rinv[i]   = 1.0f / (float)max(cnt[i], 1);
        cursor[i] = rowptr[i];
    }
}

__global__ void fill_kernel(const int* __restrict__ src, const int* __restrict__ dst,
                            int* __restrict__ cursor, int* __restrict__ csr_src) {
    long long stride = (long long)gridDim.x * blockDim.x;
    for (long long e = (long long)blockIdx.x * blockDim.x + threadIdx.x; e < N_EDGES; e += stride) {
        int d = dst[e];
        int p = atomicAdd(&cursor[d], 1);
        csr_src[p] = src[e];
    }
}

// ---------------- gather aggregation: one wave per dst node ----------------
// After fill, cursor[n] == row end. agg[n] = rinv[n] * sum_{e in row} h[src_e]
__launch_bounds__(256)
__global__ void agg_kernel(const int* __restrict__ rowptr, const int* __restrict__ rowend,
                           const int* __restrict__ csr_src, const float* __restrict__ rinv,
                           const float* __restrict__ h, float* __restrict__ agg) {
    int node = blockIdx.x * 4 + (threadIdx.x >> 6);
    int lane = threadIdx.x & 63;
    if (node >= N_NODES) return;
    int beg = rowptr[node];
    int end = rowend[node];
    float4 acc = make_float4(0.f, 0.f, 0.f, 0.f);
    int p = beg;
    for (; p + 1 < end; p += 2) {
        int s0 = csr_src[p];
        int s1 = csr_src[p + 1];
        float4 v0 = *(const float4*)(h + (size_t)s0 * DIN + lane * 4);
        float4 v1 = *(const float4*)(h + (size_t)s1 * DIN + lane * 4);
        acc.x += v0.x + v1.x; acc.y += v0.y + v1.y;
        acc.z += v0.z + v1.z; acc.w += v0.w + v1.w;
    }
    if (p < end) {
        int s0 = csr_src[p];
        float4 v0 = *(const float4*)(h + (size_t)s0 * DIN + lane * 4);
        acc.x += v0.x; acc.y += v0.y; acc.z += v0.z; acc.w += v0.w;
    }
    float r = rinv[node];
    acc.x *= r; acc.y *= r; acc.z *= r; acc.w *= r;
    *(float4*)(agg + (size_t)node * DIN + lane * 4) = acc;
}

// ---------------- fused dual GEMM ----------------
// out[row, col] = act( sum_k agg[row,k]*Wl[col,k] + sum_k h[row,k]*Wr[col,k] + b[col] )
// Virtual K = 512: k<256 -> (agg, Wl); k>=256 -> (h, Wr). agg pre-normalized.
#define BM 64
#define BN 64
#define BK 32

__launch_bounds__(256)
__global__ void sage_gemm(const float* __restrict__ Agg, const float* __restrict__ H,
                          const float* __restrict__ Wl, const float* __restrict__ Wr,
                          const float* __restrict__ bias, float* __restrict__ out,
                          int dout, int do_relu) {
    __shared__ float sA[BK][BM + 1];
    __shared__ float sB[BK][BN + 1];

    const int row0 = blockIdx.x * BM;
    const int col0 = blockIdx.y * BN;
    const int t  = threadIdx.x;
    const int tx = t & 15;
    const int ty = t >> 4;

    float acc[4][4] = {};

    for (int kt = 0; kt < 512; kt += BK) {
        #pragma unroll
        for (int i = 0; i < 2; ++i) {
            int idx = t + i * 256;       // 0..511
            int r   = idx >> 3;          // 0..63
            int kc  = (idx & 7) * 4;     // 0,4,...,28
            int row = row0 + r;
            int kk  = kt + kc;
            float4 v = make_float4(0.f, 0.f, 0.f, 0.f);
            if (row < N_NODES) {
                if (kk < 256) v = *(const float4*)(Agg + (size_t)row * DIN + kk);
                else          v = *(const float4*)(H + (size_t)row * DIN + (kk - 256));
            }
            sA[kc + 0][r] = v.x; sA[kc + 1][r] = v.y;
            sA[kc + 2][r] = v.z; sA[kc + 3][r] = v.w;
        }
        #pragma unroll
        for (int i = 0; i < 2; ++i) {
            int idx = t + i * 256;
            int c   = idx >> 3;
            int kc  = (idx & 7) * 4;
            int col = col0 + c;
            int kk  = kt + kc;
            float4 v;
            if (kk < 256) v = *(const float4*)(Wl + (size_t)col * DIN + kk);
            else          v = *(const float4*)(Wr + (size_t)col * DIN + (kk - 256));
            sB[kc + 0][c] = v.x; sB[kc + 1][c] = v.y;
            sB[kc + 2][c] = v.z; sB[kc + 3][c] = v.w;
        }
        __syncthreads();

        #pragma unroll
        for (int k = 0; k < BK; ++k) {
            float a[4], bb[4];
            #pragma unroll
            for (int i = 0; i < 4; ++i) a[i] = sA[k][ty * 4 + i];
            #pragma unroll
            for (int j = 0; j < 4; ++j) bb[j] = sB[k][tx * 4 + j];
            #pragma unroll
            for (int i = 0; i < 4; ++i)
                #pragma unroll
                for (int j = 0; j < 4; ++j)
                    acc[i][j] += a[i] * bb[j];
        }
        __syncthreads();
    }

    #pragma unroll
    for (int i = 0; i < 4; ++i) {
        int row = row0 + ty * 4 + i;
        if (row >= N_NODES) continue;
        #pragma unroll
        for (int j = 0; j < 4; ++j) {
            int col = col0 + tx * 4 + j;
            float v = acc[i][j] + bias[col];
            if (do_relu) v = fmaxf(v, 0.0f);
            out[(size_t)row * dout + col] = v;
        }
    }
}

// ---------------- classifier: sigmoid(h3 . Wc + bc) ----------------
__global__ void cls_kernel(const float* __restrict__ h3, const float* __restrict__ Wc,
                           const float* __restrict__ bc, float* __restrict__ out) {
    __shared__ float sW[128];
    int t = threadIdx.x;
    if (t < 128) sW[t] = Wc[t];
    __syncthreads();
    int row  = blockIdx.x * 8 + (t >> 5);
    int lane = t & 31;
    if (row >= N_NODES) return;
    float4 v = *(const float4*)(h3 + (size_t)row * 128 + lane * 4);
    float4 w = *(const float4*)(sW + lane * 4);
    float s = v.x * w.x + v.y * w.y + v.z * w.z + v.w * w.w;
    #pragma unroll
    for (int off = 16; off; off >>= 1) s += __shfl_xor(s, off, 32);
    if (lane == 0) {
        float z = s + bc[0];
        out[row] = 1.0f / (1.0f + expf(-z));
    }
}

extern "C" void kernel_launch(void* const* d_in, const int* in_sizes, int n_in,
                              void* d_out, int out_size, void* d_ws, size_t ws_size,
                              hipStream_t stream) {
    const float* x   = (const float*)d_in[0];
    const int*   ei  = (const int*)d_in[1];
    const float* Wl0 = (const float*)d_in[2];
    const float* Wr0 = (const float*)d_in[3];
    const float* b0  = (const float*)d_in[4];
    const float* Wl1 = (const float*)d_in[5];
    const float* Wr1 = (const float*)d_in[6];
    const float* b1  = (const float*)d_in[7];
    const float* Wl2 = (const float*)d_in[8];
    const float* Wr2 = (const float*)d_in[9];
    const float* b2  = (const float*)d_in[10];
    const float* Wc  = (const float*)d_in[11];
    const float* bc  = (const float*)d_in[12];
    float* out = (float*)d_out;

    const int* src = ei;             // edge_index[0]
    const int* dst = ei + N_EDGES;   // edge_index[1]

    // workspace layout
    int*   cnt    = (int*)d_ws;                    // N_PAD ints
    int*   rowptr = cnt + N_PAD;                   // N_PAD
    int*   cursor = rowptr + N_PAD;                // N_PAD (becomes rowend after fill)
    int*   bsums  = cursor + N_PAD;                // 512
    int*   csr    = bsums + 512;                   // N_EDGES
    float* rinv   = (float*)(csr + N_EDGES);       // N_PAD
    float* bufA   = rinv + N_PAD;                  // agg: N*256
    float* bufB   = bufA + (size_t)N_NODES * 256;  // h1 / h3
    float* bufC   = bufB + (size_t)N_NODES * 256;  // h2

    const int nscan = (N_NODES + 255) / 256;  // 391 blocks

    // ---- CSR build (once; graph fixed across layers) ----
    hipMemsetAsync(cnt, 0, N_PAD * sizeof(int), stream);
    hist_kernel<<<2048, 256, 0, stream>>>(dst, cnt);
    scan1_kernel<<<nscan, 256, 0, stream>>>(cnt, rowptr, bsums);
    scan2_kernel<<<1, 512, 0, stream>>>(bsums, nscan);
    scan3_kernel<<<nscan, 256, 0, stream>>>(rowptr, bsums);
    rinv_copy_kernel<<<nscan, 256, 0, stream>>>(cnt, rinv, rowptr, cursor);
    fill_kernel<<<2048, 256, 0, stream>>>(src, dst, cursor, csr);

    dim3 gemm_grid((N_NODES + BM - 1) / BM, 4);
    dim3 gemm_grid2((N_NODES + BM - 1) / BM, 2);
    const int agg_blocks = (N_NODES + 3) / 4;

    // ---- layer 0 ----
    agg_kernel<<<agg_blocks, 256, 0, stream>>>(rowptr, cursor, csr, rinv, x, bufA);
    sage_gemm<<<gemm_grid, 256, 0, stream>>>(bufA, x, Wl0, Wr0, b0, bufB, 256, 1);

    // ---- layer 1 ----
    agg_kernel<<<agg_blocks, 256, 0, stream>>>(rowptr, cursor, csr, rinv, bufB, bufA);
    sage_gemm<<<gemm_grid, 256, 0, stream>>>(bufA, bufB, Wl1, Wr1, b1, bufC, 256, 1);

    // ---- layer 2 (no relu), 128-dim out into bufB ----
    agg_kernel<<<agg_blocks, 256, 0, stream>>>(rowptr, cursor, csr, rinv, bufC, bufA);
    sage_gemm<<<gemm_grid2, 256, 0, stream>>>(bufA, bufC, Wl2, Wr2, b2, bufB, 128, 0);

    // ---- classifier ----
    cls_kernel<<<(N_NODES + 7) / 8, 256, 0, stream>>>(bufB, Wc, bc, out);
}

// Round 4
// 736.272 us; speedup vs baseline: 23.9573x; 3.1168x over previous
//
#include <hip/hip_runtime.h>
#include <math.h>

#define N_NODES 100000
#define N_PAD   100352   // N rounded up to multiple of 256
#define N_EDGES 1600000
#define DIN 256

typedef unsigned short u16;
typedef __attribute__((ext_vector_type(8))) short bf16x8;
typedef __attribute__((ext_vector_type(4))) float f32x4;

__device__ __forceinline__ float b2f(u16 u) {
    union { unsigned int i; float f; } c; c.i = ((unsigned int)u) << 16; return c.f;
}
__device__ __forceinline__ u16 f2b(float f) {
    union { float f; unsigned int i; } c; c.f = f;
    unsigned int x = c.i;
    return (u16)((x + 0x7fffu + ((x >> 16) & 1u)) >> 16);   // RNE
}

// ---------------- f32 -> bf16 conversion ----------------
__global__ void cvt_kernel(const float* __restrict__ in, u16* __restrict__ out, int n4) {
    int i = blockIdx.x * blockDim.x + threadIdx.x;
    if (i < n4) {
        float4 v = ((const float4*)in)[i];
        ushort4 o;
        o.x = f2b(v.x); o.y = f2b(v.y); o.z = f2b(v.z); o.w = f2b(v.w);
        ((ushort4*)out)[i] = o;
    }
}

// ---------------- CSR build ----------------
__global__ void hist_kernel(const int* __restrict__ dst, int* __restrict__ cnt) {
    long long stride = (long long)gridDim.x * blockDim.x;
    for (long long e = (long long)blockIdx.x * blockDim.x + threadIdx.x; e < N_EDGES; e += stride)
        atomicAdd(&cnt[dst[e]], 1);
}

__global__ void scan1_kernel(const int* __restrict__ cnt, int* __restrict__ excl,
                             int* __restrict__ blocksums) {
    __shared__ int s[256];
    int tid = threadIdx.x;
    int i = blockIdx.x * 256 + tid;
    int v = (i < N_NODES) ? cnt[i] : 0;
    s[tid] = v;
    __syncthreads();
    for (int off = 1; off < 256; off <<= 1) {
        int t = (tid >= off) ? s[tid - off] : 0;
        __syncthreads();
        s[tid] += t;
        __syncthreads();
    }
    if (i < N_NODES) excl[i] = s[tid] - v;
    if (tid == 255) blocksums[blockIdx.x] = s[255];
}

__global__ void scan2_kernel(int* __restrict__ blocksums, int nb) {
    __shared__ int s[512];
    int tid = threadIdx.x;
    int v = (tid < nb) ? blocksums[tid] : 0;
    s[tid] = v;
    __syncthreads();
    for (int off = 1; off < 512; off <<= 1) {
        int t = (tid >= off) ? s[tid - off] : 0;
        __syncthreads();
        s[tid] += t;
        __syncthreads();
    }
    if (tid < nb) blocksums[tid] = s[tid] - v;   // exclusive
}

__global__ void scan3_kernel(int* __restrict__ excl, const int* __restrict__ blocksums) {
    int i = blockIdx.x * 256 + threadIdx.x;
    if (i < N_NODES) excl[i] += blocksums[blockIdx.x];
}

__global__ void rinv_copy_kernel(const int* __restrict__ cnt, float* __restrict__ rinv,
                                 const int* __restrict__ rowptr, int* __restrict__ cursor) {
    int i = blockIdx.x * 256 + threadIdx.x;
    if (i < N_NODES) {
        rinv[i]   = 1.0f / (float)max(cnt[i], 1);
        cursor[i] = rowptr[i];
    }
}

__global__ void fill_kernel(const int* __restrict__ src, const int* __restrict__ dst,
                            int* __restrict__ cursor, int* __restrict__ csr_src) {
    long long stride = (long long)gridDim.x * blockDim.x;
    for (long long e = (long long)blockIdx.x * blockDim.x + threadIdx.x; e < N_EDGES; e += stride) {
        int d = dst[e];
        int p = atomicAdd(&cursor[d], 1);
        csr_src[p] = src[e];
    }
}

// ---------------- gather aggregation (bf16 in, bf16 out, f32 accum) ----------------
__launch_bounds__(256)
__global__ void agg_kernel(const int* __restrict__ rowptr, const int* __restrict__ rowend,
                           const int* __restrict__ csr_src, const float* __restrict__ rinv,
                           const u16* __restrict__ h, u16* __restrict__ agg) {
    int node = blockIdx.x * 4 + (threadIdx.x >> 6);
    int lane = threadIdx.x & 63;
    if (node >= N_NODES) return;
    int beg = rowptr[node];
    int end = rowend[node];
    float a0 = 0.f, a1 = 0.f, a2 = 0.f, a3 = 0.f;
    int p = beg;
    for (; p + 1 < end; p += 2) {
        int s0 = csr_src[p];
        int s1 = csr_src[p + 1];
        ushort4 v0 = *(const ushort4*)(h + (size_t)s0 * DIN + lane * 4);
        ushort4 v1 = *(const ushort4*)(h + (size_t)s1 * DIN + lane * 4);
        a0 += b2f(v0.x) + b2f(v1.x);
        a1 += b2f(v0.y) + b2f(v1.y);
        a2 += b2f(v0.z) + b2f(v1.z);
        a3 += b2f(v0.w) + b2f(v1.w);
    }
    if (p < end) {
        int s0 = csr_src[p];
        ushort4 v0 = *(const ushort4*)(h + (size_t)s0 * DIN + lane * 4);
        a0 += b2f(v0.x); a1 += b2f(v0.y); a2 += b2f(v0.z); a3 += b2f(v0.w);
    }
    float r = rinv[node];
    ushort4 o;
    o.x = f2b(a0 * r); o.y = f2b(a1 * r); o.z = f2b(a2 * r); o.w = f2b(a3 * r);
    *(ushort4*)(agg + (size_t)node * DIN + lane * 4) = o;
}

// ---------------- MFMA dual GEMM ----------------
// out[row,col] = act( sum_k agg[row,k]*Wl[col,k] + h[row,k]*Wr[col,k] + b[col] )
// Virtual K=512: kt<256 -> (agg, Wl), else (h, Wr). 128x128 tile, 4 waves (2x2),
// each wave 64x64 = 4x4 fragments of mfma_f32_16x16x32_bf16.
// LDS rows padded to 40 bf16 (80B): 16B-aligned.
template <bool OUT_F32>
__launch_bounds__(256)
__global__ void sage_gemm(const u16* __restrict__ Agg, const u16* __restrict__ H,
                          const u16* __restrict__ Wl, const u16* __restrict__ Wr,
                          const float* __restrict__ bias, void* __restrict__ outp,
                          int dout, int do_relu) {
    __shared__ u16 sA[128 * 40];
    __shared__ u16 sB[128 * 40];

    const int t    = threadIdx.x;
    const int row0 = blockIdx.x * 128;
    const int col0 = blockIdx.y * 128;
    const int w    = t >> 6, lane = t & 63;
    const int wr   = w >> 1, wc = w & 1;
    const int lr   = lane & 15, lg = lane >> 4;

    f32x4 acc[4][4] = {};

    for (int kt = 0; kt < 512; kt += 32) {
        const u16* Asrc = (kt < 256) ? Agg : H;
        const u16* Bsrc = (kt < 256) ? Wl  : Wr;
        const int  kb   = (kt < 256) ? kt  : kt - 256;
        #pragma unroll
        for (int i = 0; i < 2; ++i) {
            int idx = i * 256 + t;          // 0..511
            int r   = idx >> 2;             // 0..127
            int ko  = (idx & 3) * 8;        // 0,8,16,24
            uint4 va = *(const uint4*)(Asrc + (size_t)(row0 + r) * DIN + kb + ko);
            *(uint4*)&sA[r * 40 + ko] = va;
            uint4 vb = *(const uint4*)(Bsrc + (size_t)(col0 + r) * DIN + kb + ko);
            *(uint4*)&sB[r * 40 + ko] = vb;
        }
        __syncthreads();

        bf16x8 af[4], bfr[4];
        #pragma unroll
        for (int m = 0; m < 4; ++m)
            af[m] = *(const bf16x8*)&sA[(wr * 64 + m * 16 + lr) * 40 + lg * 8];
        #pragma unroll
        for (int n = 0; n < 4; ++n)
            bfr[n] = *(const bf16x8*)&sB[(wc * 64 + n * 16 + lr) * 40 + lg * 8];
        #pragma unroll
        for (int m = 0; m < 4; ++m)
            #pragma unroll
            for (int n = 0; n < 4; ++n)
                acc[m][n] = __builtin_amdgcn_mfma_f32_16x16x32_bf16(af[m], bfr[n], acc[m][n], 0, 0, 0);
        __syncthreads();
    }

    // epilogue: C/D layout col=lane&15, row=(lane>>4)*4+reg (m89-verified)
    #pragma unroll
    for (int m = 0; m < 4; ++m) {
        int row = row0 + wr * 64 + m * 16 + lg * 4;
        #pragma unroll
        for (int n = 0; n < 4; ++n) {
            int col = col0 + wc * 64 + n * 16 + lr;
            float bcol = bias[col];
            #pragma unroll
            for (int r = 0; r < 4; ++r) {
                float v = acc[m][n][r] + bcol;
                if (do_relu) v = fmaxf(v, 0.0f);
                if (OUT_F32) ((float*)outp)[(size_t)(row + r) * dout + col] = v;
                else         ((u16*)outp)[(size_t)(row + r) * dout + col] = f2b(v);
            }
        }
    }
}

// ---------------- classifier: sigmoid(h3 . Wc + bc), h3 in f32 ----------------
__global__ void cls_kernel(const float* __restrict__ h3, const float* __restrict__ Wc,
                           const float* __restrict__ bc, float* __restrict__ out) {
    __shared__ float sW[128];
    int t = threadIdx.x;
    if (t < 128) sW[t] = Wc[t];
    __syncthreads();
    int row  = blockIdx.x * 8 + (t >> 5);
    int lane = t & 31;
    if (row >= N_NODES) return;
    float4 v = *(const float4*)(h3 + (size_t)row * 128 + lane * 4);
    float4 w = *(const float4*)(sW + lane * 4);
    float s = v.x * w.x + v.y * w.y + v.z * w.z + v.w * w.w;
    #pragma unroll
    for (int off = 16; off; off >>= 1) s += __shfl_xor(s, off, 32);
    if (lane == 0) {
        float z = s + bc[0];
        out[row] = 1.0f / (1.0f + expf(-z));
    }
}

extern "C" void kernel_launch(void* const* d_in, const int* in_sizes, int n_in,
                              void* d_out, int out_size, void* d_ws, size_t ws_size,
                              hipStream_t stream) {
    const float* x   = (const float*)d_in[0];
    const int*   ei  = (const int*)d_in[1];
    const float* Wl0 = (const float*)d_in[2];
    const float* Wr0 = (const float*)d_in[3];
    const float* b0  = (const float*)d_in[4];
    const float* Wl1 = (const float*)d_in[5];
    const float* Wr1 = (const float*)d_in[6];
    const float* b1  = (const float*)d_in[7];
    const float* Wl2 = (const float*)d_in[8];
    const float* Wr2 = (const float*)d_in[9];
    const float* b2  = (const float*)d_in[10];
    const float* Wc  = (const float*)d_in[11];
    const float* bc  = (const float*)d_in[12];
    float* out = (float*)d_out;

    const int* src = ei;             // edge_index[0]
    const int* dst = ei + N_EDGES;   // edge_index[1]

    // ---- workspace layout ----
    int*   cnt    = (int*)d_ws;                    // N_PAD
    int*   rowptr = cnt + N_PAD;                   // N_PAD
    int*   cursor = rowptr + N_PAD;                // N_PAD (rowend after fill)
    int*   bsums  = cursor + N_PAD;                // 512
    int*   csr    = bsums + 512;                   // N_EDGES
    float* rinv   = (float*)(csr + N_EDGES);       // N_PAD
    u16*   xb     = (u16*)(rinv + N_PAD);          // N_PAD*256
    u16*   wb     = xb + (size_t)N_PAD * 256;      // 327680 (6 weights)
    u16*   bufA   = wb + 327680;                   // agg
    u16*   bufB   = bufA + (size_t)N_PAD * 256;    // h1 / h3(f32,128)
    u16*   bufC   = bufB + (size_t)N_PAD * 256;    // h2

    u16* wl0 = wb;
    u16* wr0 = wl0 + 65536;
    u16* wl1 = wr0 + 65536;
    u16* wr1 = wl1 + 65536;
    u16* wl2 = wr1 + 65536;
    u16* wr2 = wl2 + 32768;                        // FIX: layer-2 weights are 128x256

    const int nscan = (N_NODES + 255) / 256;       // 391

    // ---- conversions (bf16) ----
    cvt_kernel<<<(N_NODES * 64 + 255) / 256, 256, 0, stream>>>(x, xb, N_NODES * 64);
    cvt_kernel<<<64, 256, 0, stream>>>(Wl0, wl0, 16384);
    cvt_kernel<<<64, 256, 0, stream>>>(Wr0, wr0, 16384);
    cvt_kernel<<<64, 256, 0, stream>>>(Wl1, wl1, 16384);
    cvt_kernel<<<64, 256, 0, stream>>>(Wr1, wr1, 16384);
    cvt_kernel<<<32, 256, 0, stream>>>(Wl2, wl2, 8192);
    cvt_kernel<<<32, 256, 0, stream>>>(Wr2, wr2, 8192);

    // ---- CSR build ----
    hipMemsetAsync(cnt, 0, N_PAD * sizeof(int), stream);
    hist_kernel<<<2048, 256, 0, stream>>>(dst, cnt);
    scan1_kernel<<<nscan, 256, 0, stream>>>(cnt, rowptr, bsums);
    scan2_kernel<<<1, 512, 0, stream>>>(bsums, nscan);
    scan3_kernel<<<nscan, 256, 0, stream>>>(rowptr, bsums);
    rinv_copy_kernel<<<nscan, 256, 0, stream>>>(cnt, rinv, rowptr, cursor);
    fill_kernel<<<2048, 256, 0, stream>>>(src, dst, cursor, csr);

    const int Mblocks = (N_NODES + 127) / 128;     // 782
    dim3 g01(Mblocks, 2);                          // dout=256
    dim3 g2(Mblocks, 1);                           // dout=128
    const int agg_blocks = (N_NODES + 3) / 4;

    // ---- layer 0 ----
    agg_kernel<<<agg_blocks, 256, 0, stream>>>(rowptr, cursor, csr, rinv, xb, bufA);
    sage_gemm<false><<<g01, 256, 0, stream>>>(bufA, xb, wl0, wr0, b0, bufB, 256, 1);

    // ---- layer 1 ----
    agg_kernel<<<agg_blocks, 256, 0, stream>>>(rowptr, cursor, csr, rinv, bufB, bufA);
    sage_gemm<false><<<g01, 256, 0, stream>>>(bufA, bufB, wl1, wr1, b1, bufC, 256, 1);

    // ---- layer 2 (no relu, dout=128, f32 out for classifier precision) ----
    agg_kernel<<<agg_blocks, 256, 0, stream>>>(rowptr, cursor, csr, rinv, bufC, bufA);
    sage_gemm<true><<<g2, 256, 0, stream>>>(bufA, bufC, wl2, wr2, b2, bufB, 128, 0);

    // ---- classifier ----
    cls_kernel<<<(N_NODES + 7) / 8, 256, 0, stream>>>((const float*)bufB, Wc, bc, out);
}

// Round 5
// 631.064 us; speedup vs baseline: 27.9513x; 1.1667x over previous
//
#include <hip/hip_runtime.h>
#include <math.h>

#define N_NODES 100000
#define N_PAD   100352
#define N_EDGES 1600000
#define DIN 256

// CSR bucket-partition parameters
#define NB 782        // buckets of 128 dst nodes: ceil(100000/128)
#define NC 256        // edge chunks
#define CHUNK 6250    // N_EDGES / NC exactly
#define MT_N (NB * NC) // 200192
#define MT_PAD 200448  // 783 * 256

typedef unsigned short u16;
typedef unsigned int u32;
typedef __attribute__((ext_vector_type(8))) short bf16x8;
typedef __attribute__((ext_vector_type(4))) float f32x4;

__device__ __forceinline__ float b2f(u16 u) {
    union { unsigned int i; float f; } c; c.i = ((unsigned int)u) << 16; return c.f;
}
__device__ __forceinline__ u16 f2b(float f) {
    union { float f; unsigned int i; } c; c.f = f;
    unsigned int x = c.i;
    return (u16)((x + 0x7fffu + ((x >> 16) & 1u)) >> 16);   // RNE
}

// ---------------- f32 -> bf16 conversion ----------------
__global__ void cvt_kernel(const float* __restrict__ in, u16* __restrict__ out, int n4) {
    int i = blockIdx.x * blockDim.x + threadIdx.x;
    if (i < n4) {
        float4 v = ((const float4*)in)[i];
        ushort4 o;
        o.x = f2b(v.x); o.y = f2b(v.y); o.z = f2b(v.z); o.w = f2b(v.w);
        ((ushort4*)out)[i] = o;
    }
}

// ---------------- CSR build: atomic-free bucket partition ----------------
// P1: per-chunk LDS histogram over NB buckets -> MT[b*NC + c]
__launch_bounds__(256)
__global__ void p1_hist(const int* __restrict__ dst, int* __restrict__ MT) {
    __shared__ int bins[NB];
    const int c = blockIdx.x, tid = threadIdx.x;
    for (int b = tid; b < NB; b += 256) bins[b] = 0;
    __syncthreads();
    const int e0 = c * CHUNK;
    for (int e = e0 + tid; e < e0 + CHUNK; e += 256)
        atomicAdd(&bins[dst[e] >> 7], 1);
    __syncthreads();
    for (int b = tid; b < NB; b += 256) MT[b * NC + c] = bins[b];
}

__global__ void scan1_kernel(const int* __restrict__ in, int* __restrict__ excl,
                             int* __restrict__ blocksums, int n) {
    __shared__ int s[256];
    int tid = threadIdx.x;
    int i = blockIdx.x * 256 + tid;
    int v = (i < n) ? in[i] : 0;
    s[tid] = v;
    __syncthreads();
    for (int off = 1; off < 256; off <<= 1) {
        int t = (tid >= off) ? s[tid - off] : 0;
        __syncthreads();
        s[tid] += t;
        __syncthreads();
    }
    if (i < n) excl[i] = s[tid] - v;
    if (tid == 255) blocksums[blockIdx.x] = s[255];
}

// sequential-carry exclusive scan over nb block sums (single block)
__global__ void scan_carry_kernel(int* __restrict__ bsums, int nb) {
    __shared__ int s[256];
    int tid = threadIdx.x;
    int carry = 0;
    for (int base = 0; base < nb; base += 256) {
        int i = base + tid;
        int v = (i < nb) ? bsums[i] : 0;
        s[tid] = v;
        __syncthreads();
        for (int off = 1; off < 256; off <<= 1) {
            int t = (tid >= off) ? s[tid - off] : 0;
            __syncthreads();
            s[tid] += t;
            __syncthreads();
        }
        int incl = s[tid];
        int tot = s[255];
        if (i < nb) bsums[i] = incl - v + carry;
        carry += tot;
        __syncthreads();
    }
}

__global__ void scan3_kernel(int* __restrict__ excl, const int* __restrict__ blocksums, int n) {
    int i = blockIdx.x * 256 + threadIdx.x;
    if (i < n) excl[i] += blocksums[blockIdx.x];
}

// P2: partition edges by bucket using LDS cursors (no global atomics)
__launch_bounds__(256)
__global__ void p2_partition(const int* __restrict__ src, const int* __restrict__ dst,
                             const int* __restrict__ scanMT, u32* __restrict__ csr_tmp) {
    __shared__ int cur[NB];
    const int c = blockIdx.x, tid = threadIdx.x;
    for (int b = tid; b < NB; b += 256) cur[b] = scanMT[b * NC + c];
    __syncthreads();
    const int e0 = c * CHUNK;
    for (int e = e0 + tid; e < e0 + CHUNK; e += 256) {
        int d = dst[e];
        int pos = atomicAdd(&cur[d >> 7], 1);   // LDS atomic
        csr_tmp[pos] = ((u32)(d & 127) << 25) | (u32)src[e];
    }
}

// P3: per-bucket exact CSR: 128-bin count + scan + scatter; rowptr/rowend/rinv
__launch_bounds__(256)
__global__ void p3_csr(const int* __restrict__ scanMT, const u32* __restrict__ csr_tmp,
                       int* __restrict__ csr, int* __restrict__ rowptr,
                       int* __restrict__ rowend, float* __restrict__ rinv) {
    __shared__ int cnt[128];
    __shared__ int excl[128];
    __shared__ int cur[128];
    const int b = blockIdx.x, tid = threadIdx.x;
    const int beg = scanMT[b * NC];
    const int end = (b == NB - 1) ? N_EDGES : scanMT[(b + 1) * NC];
    if (tid < 128) cnt[tid] = 0;
    __syncthreads();
    for (int e = beg + tid; e < end; e += 256)
        atomicAdd(&cnt[csr_tmp[e] >> 25], 1);
    __syncthreads();
    if (tid == 0) {
        int run = 0;
        for (int i = 0; i < 128; ++i) { excl[i] = run; run += cnt[i]; }
    }
    __syncthreads();
    if (tid < 128) cur[tid] = beg + excl[tid];
    __syncthreads();
    for (int e = beg + tid; e < end; e += 256) {
        u32 v = csr_tmp[e];
        int pos = atomicAdd(&cur[v >> 25], 1);  // LDS atomic
        csr[pos] = (int)(v & 0x1FFFFFFu);
    }
    if (tid < 128) {
        int node = b * 128 + tid;
        if (node < N_NODES) {
            int rp = beg + excl[tid];
            rowptr[node] = rp;
            rowend[node] = rp + cnt[tid];
            rinv[node]   = 1.0f / (float)max(cnt[tid], 1);
        }
    }
}

// ---------------- gather aggregation (bf16 in, bf16 out, f32 accum) ----------------
__launch_bounds__(256)
__global__ void agg_kernel(const int* __restrict__ rowptr, const int* __restrict__ rowend,
                           const int* __restrict__ csr_src, const float* __restrict__ rinv,
                           const u16* __restrict__ h, u16* __restrict__ agg) {
    int node = blockIdx.x * 4 + (threadIdx.x >> 6);
    int lane = threadIdx.x & 63;
    if (node >= N_NODES) return;
    int beg = rowptr[node];
    int end = rowend[node];
    float a0 = 0.f, a1 = 0.f, a2 = 0.f, a3 = 0.f;
    int p = beg;
    for (; p + 1 < end; p += 2) {
        int s0 = csr_src[p];
        int s1 = csr_src[p + 1];
        ushort4 v0 = *(const ushort4*)(h + (size_t)s0 * DIN + lane * 4);
        ushort4 v1 = *(const ushort4*)(h + (size_t)s1 * DIN + lane * 4);
        a0 += b2f(v0.x) + b2f(v1.x);
        a1 += b2f(v0.y) + b2f(v1.y);
        a2 += b2f(v0.z) + b2f(v1.z);
        a3 += b2f(v0.w) + b2f(v1.w);
    }
    if (p < end) {
        int s0 = csr_src[p];
        ushort4 v0 = *(const ushort4*)(h + (size_t)s0 * DIN + lane * 4);
        a0 += b2f(v0.x); a1 += b2f(v0.y); a2 += b2f(v0.z); a3 += b2f(v0.w);
    }
    float r = rinv[node];
    ushort4 o;
    o.x = f2b(a0 * r); o.y = f2b(a1 * r); o.z = f2b(a2 * r); o.w = f2b(a3 * r);
    *(ushort4*)(agg + (size_t)node * DIN + lane * 4) = o;
}

// ---------------- MFMA dual GEMM ----------------
template <bool OUT_F32>
__launch_bounds__(256)
__global__ void sage_gemm(const u16* __restrict__ Agg, const u16* __restrict__ H,
                          const u16* __restrict__ Wl, const u16* __restrict__ Wr,
                          const float* __restrict__ bias, void* __restrict__ outp,
                          int dout, int do_relu) {
    __shared__ u16 sA[128 * 40];
    __shared__ u16 sB[128 * 40];

    const int t    = threadIdx.x;
    const int row0 = blockIdx.x * 128;
    const int col0 = blockIdx.y * 128;
    const int w    = t >> 6, lane = t & 63;
    const int wr   = w >> 1, wc = w & 1;
    const int lr   = lane & 15, lg = lane >> 4;

    f32x4 acc[4][4] = {};

    for (int kt = 0; kt < 512; kt += 32) {
        const u16* Asrc = (kt < 256) ? Agg : H;
        const u16* Bsrc = (kt < 256) ? Wl  : Wr;
        const int  kb   = (kt < 256) ? kt  : kt - 256;
        #pragma unroll
        for (int i = 0; i < 2; ++i) {
            int idx = i * 256 + t;
            int r   = idx >> 2;
            int ko  = (idx & 3) * 8;
            uint4 va = *(const uint4*)(Asrc + (size_t)(row0 + r) * DIN + kb + ko);
            *(uint4*)&sA[r * 40 + ko] = va;
            uint4 vb = *(const uint4*)(Bsrc + (size_t)(col0 + r) * DIN + kb + ko);
            *(uint4*)&sB[r * 40 + ko] = vb;
        }
        __syncthreads();

        bf16x8 af[4], bfr[4];
        #pragma unroll
        for (int m = 0; m < 4; ++m)
            af[m] = *(const bf16x8*)&sA[(wr * 64 + m * 16 + lr) * 40 + lg * 8];
        #pragma unroll
        for (int n = 0; n < 4; ++n)
            bfr[n] = *(const bf16x8*)&sB[(wc * 64 + n * 16 + lr) * 40 + lg * 8];
        #pragma unroll
        for (int m = 0; m < 4; ++m)
            #pragma unroll
            for (int n = 0; n < 4; ++n)
                acc[m][n] = __builtin_amdgcn_mfma_f32_16x16x32_bf16(af[m], bfr[n], acc[m][n], 0, 0, 0);
        __syncthreads();
    }

    #pragma unroll
    for (int m = 0; m < 4; ++m) {
        int row = row0 + wr * 64 + m * 16 + lg * 4;
        #pragma unroll
        for (int n = 0; n < 4; ++n) {
            int col = col0 + wc * 64 + n * 16 + lr;
            float bcol = bias[col];
            #pragma unroll
            for (int r = 0; r < 4; ++r) {
                float v = acc[m][n][r] + bcol;
                if (do_relu) v = fmaxf(v, 0.0f);
                if (OUT_F32) ((float*)outp)[(size_t)(row + r) * dout + col] = v;
                else         ((u16*)outp)[(size_t)(row + r) * dout + col] = f2b(v);
            }
        }
    }
}

// ---------------- classifier ----------------
__global__ void cls_kernel(const float* __restrict__ h3, const float* __restrict__ Wc,
                           const float* __restrict__ bc, float* __restrict__ out) {
    __shared__ float sW[128];
    int t = threadIdx.x;
    if (t < 128) sW[t] = Wc[t];
    __syncthreads();
    int row  = blockIdx.x * 8 + (t >> 5);
    int lane = t & 31;
    if (row >= N_NODES) return;
    float4 v = *(const float4*)(h3 + (size_t)row * 128 + lane * 4);
    float4 w = *(const float4*)(sW + lane * 4);
    float s = v.x * w.x + v.y * w.y + v.z * w.z + v.w * w.w;
    #pragma unroll
    for (int off = 16; off; off >>= 1) s += __shfl_xor(s, off, 32);
    if (lane == 0) {
        float z = s + bc[0];
        out[row] = 1.0f / (1.0f + expf(-z));
    }
}

extern "C" void kernel_launch(void* const* d_in, const int* in_sizes, int n_in,
                              void* d_out, int out_size, void* d_ws, size_t ws_size,
                              hipStream_t stream) {
    const float* x   = (const float*)d_in[0];
    const int*   ei  = (const int*)d_in[1];
    const float* Wl0 = (const float*)d_in[2];
    const float* Wr0 = (const float*)d_in[3];
    const float* b0  = (const float*)d_in[4];
    const float* Wl1 = (const float*)d_in[5];
    const float* Wr1 = (const float*)d_in[6];
    const float* b1  = (const float*)d_in[7];
    const float* Wl2 = (const float*)d_in[8];
    const float* Wr2 = (const float*)d_in[9];
    const float* b2  = (const float*)d_in[10];
    const float* Wc  = (const float*)d_in[11];
    const float* bc  = (const float*)d_in[12];
    float* out = (float*)d_out;

    const int* src = ei;             // edge_index[0]
    const int* dst = ei + N_EDGES;   // edge_index[1]

    // ---- workspace layout ----
    int*   MT     = (int*)d_ws;                    // MT_PAD
    int*   MTs    = MT + MT_PAD;                   // MT_PAD (scanned)
    int*   bsums  = MTs + MT_PAD;                  // 1024
    u32*   csrtmp = (u32*)(bsums + 1024);          // N_EDGES
    int*   csr    = (int*)(csrtmp + N_EDGES);      // N_EDGES
    int*   rowptr = csr + N_EDGES;                 // N_PAD
    int*   rowend = rowptr + N_PAD;                // N_PAD
    float* rinv   = (float*)(rowend + N_PAD);      // N_PAD
    u16*   xb     = (u16*)(rinv + N_PAD);          // N_PAD*256
    u16*   wb     = xb + (size_t)N_PAD * 256;      // weights
    u16*   bufA   = wb + 327680;                   // agg
    u16*   bufB   = bufA + (size_t)N_PAD * 256;    // h1 / h3(f32,128)
    u16*   bufC   = bufB + (size_t)N_PAD * 256;    // h2

    u16* wl0 = wb;
    u16* wr0 = wl0 + 65536;
    u16* wl1 = wr0 + 65536;
    u16* wr1 = wl1 + 65536;
    u16* wl2 = wr1 + 65536;
    u16* wr2 = wl2 + 32768;

    // ---- conversions (bf16) ----
    cvt_kernel<<<(N_NODES * 64 + 255) / 256, 256, 0, stream>>>(x, xb, N_NODES * 64);
    cvt_kernel<<<64, 256, 0, stream>>>(Wl0, wl0, 16384);
    cvt_kernel<<<64, 256, 0, stream>>>(Wr0, wr0, 16384);
    cvt_kernel<<<64, 256, 0, stream>>>(Wl1, wl1, 16384);
    cvt_kernel<<<64, 256, 0, stream>>>(Wr1, wr1, 16384);
    cvt_kernel<<<32, 256, 0, stream>>>(Wl2, wl2, 8192);
    cvt_kernel<<<32, 256, 0, stream>>>(Wr2, wr2, 8192);

    // ---- CSR build (atomic-free bucket partition) ----
    const int scan_blocks = (MT_N + 255) / 256;    // 783
    p1_hist<<<NC, 256, 0, stream>>>(dst, MT);
    scan1_kernel<<<scan_blocks, 256, 0, stream>>>(MT, MTs, bsums, MT_N);
    scan_carry_kernel<<<1, 256, 0, stream>>>(bsums, scan_blocks);
    scan3_kernel<<<scan_blocks, 256, 0, stream>>>(MTs, bsums, MT_N);
    p2_partition<<<NC, 256, 0, stream>>>(src, dst, MTs, csrtmp);
    p3_csr<<<NB, 256, 0, stream>>>(MTs, csrtmp, csr, rowptr, rowend, rinv);

    const int Mblocks = (N_NODES + 127) / 128;     // 782
    dim3 g01(Mblocks, 2);
    dim3 g2(Mblocks, 1);
    const int agg_blocks = (N_NODES + 3) / 4;

    // ---- layer 0 ----
    agg_kernel<<<agg_blocks, 256, 0, stream>>>(rowptr, rowend, csr, rinv, xb, bufA);
    sage_gemm<false><<<g01, 256, 0, stream>>>(bufA, xb, wl0, wr0, b0, bufB, 256, 1);

    // ---- layer 1 ----
    agg_kernel<<<agg_blocks, 256, 0, stream>>>(rowptr, rowend, csr, rinv, bufB, bufA);
    sage_gemm<false><<<g01, 256, 0, stream>>>(bufA, bufB, wl1, wr1, b1, bufC, 256, 1);

    // ---- layer 2 (no relu, dout=128, f32 out) ----
    agg_kernel<<<agg_blocks, 256, 0, stream>>>(rowptr, rowend, csr, rinv, bufC, bufA);
    sage_gemm<true><<<g2, 256, 0, stream>>>(bufA, bufC, wl2, wr2, b2, bufB, 128, 0);

    // ---- classifier ----
    cls_kernel<<<(N_NODES + 7) / 8, 256, 0, stream>>>((const float*)bufB, Wc, bc, out);
}

// Round 6
// 590.630 us; speedup vs baseline: 29.8649x; 1.0685x over previous
//
#include <hip/hip_runtime.h>
#include <math.h>

#define N_NODES 100000
#define N_PAD   100352
#define N_EDGES 1600000
#define DIN 256

// CSR bucket-partition parameters
#define NB 782        // buckets of 128 dst nodes: ceil(100000/128)
#define NC 256        // edge chunks
#define CHUNK 6250    // N_EDGES / NC exactly
#define MT_N (NB * NC)
#define MT_PAD 200448

typedef unsigned short u16;
typedef unsigned int u32;
typedef __attribute__((ext_vector_type(8))) short bf16x8;
typedef __attribute__((ext_vector_type(4))) float f32x4;

__device__ __forceinline__ float b2f(u16 u) {
    union { unsigned int i; float f; } c; c.i = ((unsigned int)u) << 16; return c.f;
}
__device__ __forceinline__ u16 f2b(float f) {
    union { float f; unsigned int i; } c; c.f = f;
    unsigned int x = c.i;
    return (u16)((x + 0x7fffu + ((x >> 16) & 1u)) >> 16);   // RNE
}

// ---------------- f32 -> bf16 conversion ----------------
__global__ void cvt_kernel(const float* __restrict__ in, u16* __restrict__ out, int n4) {
    int i = blockIdx.x * blockDim.x + threadIdx.x;
    if (i < n4) {
        float4 v = ((const float4*)in)[i];
        ushort4 o;
        o.x = f2b(v.x); o.y = f2b(v.y); o.z = f2b(v.z); o.w = f2b(v.w);
        ((ushort4*)out)[i] = o;
    }
}

// ---------------- CSR build: atomic-free bucket partition ----------------
__launch_bounds__(256)
__global__ void p1_hist(const int* __restrict__ dst, int* __restrict__ MT) {
    __shared__ int bins[NB];
    const int c = blockIdx.x, tid = threadIdx.x;
    for (int b = tid; b < NB; b += 256) bins[b] = 0;
    __syncthreads();
    const int e0 = c * CHUNK;
    for (int e = e0 + tid; e < e0 + CHUNK; e += 256)
        atomicAdd(&bins[dst[e] >> 7], 1);
    __syncthreads();
    for (int b = tid; b < NB; b += 256) MT[b * NC + c] = bins[b];
}

__global__ void scan1_kernel(const int* __restrict__ in, int* __restrict__ excl,
                             int* __restrict__ blocksums, int n) {
    __shared__ int s[256];
    int tid = threadIdx.x;
    int i = blockIdx.x * 256 + tid;
    int v = (i < n) ? in[i] : 0;
    s[tid] = v;
    __syncthreads();
    for (int off = 1; off < 256; off <<= 1) {
        int t = (tid >= off) ? s[tid - off] : 0;
        __syncthreads();
        s[tid] += t;
        __syncthreads();
    }
    if (i < n) excl[i] = s[tid] - v;
    if (tid == 255) blocksums[blockIdx.x] = s[255];
}

__global__ void scan_carry_kernel(int* __restrict__ bsums, int nb) {
    __shared__ int s[256];
    int tid = threadIdx.x;
    int carry = 0;
    for (int base = 0; base < nb; base += 256) {
        int i = base + tid;
        int v = (i < nb) ? bsums[i] : 0;
        s[tid] = v;
        __syncthreads();
        for (int off = 1; off < 256; off <<= 1) {
            int t = (tid >= off) ? s[tid - off] : 0;
            __syncthreads();
            s[tid] += t;
            __syncthreads();
        }
        int incl = s[tid];
        int tot = s[255];
        if (i < nb) bsums[i] = incl - v + carry;
        carry += tot;
        __syncthreads();
    }
}

__global__ void scan3_kernel(int* __restrict__ excl, const int* __restrict__ blocksums, int n) {
    int i = blockIdx.x * 256 + threadIdx.x;
    if (i < n) excl[i] += blocksums[blockIdx.x];
}

__launch_bounds__(256)
__global__ void p2_partition(const int* __restrict__ src, const int* __restrict__ dst,
                             const int* __restrict__ scanMT, u32* __restrict__ csr_tmp) {
    __shared__ int cur[NB];
    const int c = blockIdx.x, tid = threadIdx.x;
    for (int b = tid; b < NB; b += 256) cur[b] = scanMT[b * NC + c];
    __syncthreads();
    const int e0 = c * CHUNK;
    for (int e = e0 + tid; e < e0 + CHUNK; e += 256) {
        int d = dst[e];
        int pos = atomicAdd(&cur[d >> 7], 1);   // LDS atomic
        csr_tmp[pos] = ((u32)(d & 127) << 25) | (u32)src[e];
    }
}

__launch_bounds__(256)
__global__ void p3_csr(const int* __restrict__ scanMT, const u32* __restrict__ csr_tmp,
                       int* __restrict__ csr, int* __restrict__ rowptr,
                       int* __restrict__ rowend, float* __restrict__ rinv) {
    __shared__ int cnt[128];
    __shared__ int excl[128];
    __shared__ int cur[128];
    const int b = blockIdx.x, tid = threadIdx.x;
    const int beg = scanMT[b * NC];
    const int end = (b == NB - 1) ? N_EDGES : scanMT[(b + 1) * NC];
    if (tid < 128) cnt[tid] = 0;
    __syncthreads();
    for (int e = beg + tid; e < end; e += 256)
        atomicAdd(&cnt[csr_tmp[e] >> 25], 1);
    __syncthreads();
    if (tid == 0) {
        int run = 0;
        for (int i = 0; i < 128; ++i) { excl[i] = run; run += cnt[i]; }
    }
    __syncthreads();
    if (tid < 128) cur[tid] = beg + excl[tid];
    __syncthreads();
    for (int e = beg + tid; e < end; e += 256) {
        u32 v = csr_tmp[e];
        int pos = atomicAdd(&cur[v >> 25], 1);  // LDS atomic
        csr[pos] = (int)(v & 0x1FFFFFFu);
    }
    if (tid < 128) {
        int node = b * 128 + tid;
        if (node < N_NODES) {
            int rp = beg + excl[tid];
            rowptr[node] = rp;
            rowend[node] = rp + cnt[tid];
            rinv[node]   = 1.0f / (float)max(cnt[tid], 1);
        }
    }
}

// ---------------- gather aggregation (bf16, f32 accum), 4-deep unroll ----------------
__launch_bounds__(256)
__global__ void agg_kernel(const int* __restrict__ rowptr, const int* __restrict__ rowend,
                           const int* __restrict__ csr_src, const float* __restrict__ rinv,
                           const u16* __restrict__ h, u16* __restrict__ agg) {
    int node = blockIdx.x * 4 + (threadIdx.x >> 6);
    int lane = threadIdx.x & 63;
    if (node >= N_NODES) return;
    int beg = rowptr[node];
    int end = rowend[node];
    float a0 = 0.f, a1 = 0.f, a2 = 0.f, a3 = 0.f;
    int p = beg;
    for (; p + 3 < end; p += 4) {
        int s0 = csr_src[p], s1 = csr_src[p + 1], s2 = csr_src[p + 2], s3 = csr_src[p + 3];
        ushort4 v0 = *(const ushort4*)(h + (size_t)s0 * DIN + lane * 4);
        ushort4 v1 = *(const ushort4*)(h + (size_t)s1 * DIN + lane * 4);
        ushort4 v2 = *(const ushort4*)(h + (size_t)s2 * DIN + lane * 4);
        ushort4 v3 = *(const ushort4*)(h + (size_t)s3 * DIN + lane * 4);
        a0 += (b2f(v0.x) + b2f(v1.x)) + (b2f(v2.x) + b2f(v3.x));
        a1 += (b2f(v0.y) + b2f(v1.y)) + (b2f(v2.y) + b2f(v3.y));
        a2 += (b2f(v0.z) + b2f(v1.z)) + (b2f(v2.z) + b2f(v3.z));
        a3 += (b2f(v0.w) + b2f(v1.w)) + (b2f(v2.w) + b2f(v3.w));
    }
    for (; p < end; ++p) {
        int s0 = csr_src[p];
        ushort4 v0 = *(const ushort4*)(h + (size_t)s0 * DIN + lane * 4);
        a0 += b2f(v0.x); a1 += b2f(v0.y); a2 += b2f(v0.z); a3 += b2f(v0.w);
    }
    float r = rinv[node];
    ushort4 o;
    o.x = f2b(a0 * r); o.y = f2b(a1 * r); o.z = f2b(a2 * r); o.w = f2b(a3 * r);
    *(ushort4*)(agg + (size_t)node * DIN + lane * 4) = o;
}

// ---------------- MFMA GEMM (dual- or single-source A/B) ----------------
// DUAL: out = act([A0|A1] @ [B0|B1]^T + bias), K=512. else: out = A0 @ B0^T (+bias), K=256.
template <bool OUT_F32, bool DUAL>
__launch_bounds__(256)
__global__ void sage_gemm(const u16* __restrict__ A0, const u16* __restrict__ A1,
                          const u16* __restrict__ B0, const u16* __restrict__ B1,
                          const float* __restrict__ bias, void* __restrict__ outp,
                          int dout, int do_relu) {
    __shared__ u16 sA[128 * 40];
    __shared__ u16 sB[128 * 40];

    const int t    = threadIdx.x;
    const int row0 = blockIdx.x * 128;
    const int col0 = blockIdx.y * 128;
    const int w    = t >> 6, lane = t & 63;
    const int wr   = w >> 1, wc = w & 1;
    const int lr   = lane & 15, lg = lane >> 4;

    f32x4 acc[4][4] = {};

    const int KTOT = DUAL ? 512 : 256;
    for (int kt = 0; kt < KTOT; kt += 32) {
        const u16* Asrc = (DUAL && kt >= 256) ? A1 : A0;
        const u16* Bsrc = (DUAL && kt >= 256) ? B1 : B0;
        const int  kb   = (DUAL && kt >= 256) ? kt - 256 : kt;
        #pragma unroll
        for (int i = 0; i < 2; ++i) {
            int idx = i * 256 + t;
            int r   = idx >> 2;
            int ko  = (idx & 3) * 8;
            uint4 va = *(const uint4*)(Asrc + (size_t)(row0 + r) * DIN + kb + ko);
            *(uint4*)&sA[r * 40 + ko] = va;
            uint4 vb = *(const uint4*)(Bsrc + (size_t)(col0 + r) * DIN + kb + ko);
            *(uint4*)&sB[r * 40 + ko] = vb;
        }
        __syncthreads();

        bf16x8 af[4], bfr[4];
        #pragma unroll
        for (int m = 0; m < 4; ++m)
            af[m] = *(const bf16x8*)&sA[(wr * 64 + m * 16 + lr) * 40 + lg * 8];
        #pragma unroll
        for (int n = 0; n < 4; ++n)
            bfr[n] = *(const bf16x8*)&sB[(wc * 64 + n * 16 + lr) * 40 + lg * 8];
        #pragma unroll
        for (int m = 0; m < 4; ++m)
            #pragma unroll
            for (int n = 0; n < 4; ++n)
                acc[m][n] = __builtin_amdgcn_mfma_f32_16x16x32_bf16(af[m], bfr[n], acc[m][n], 0, 0, 0);
        __syncthreads();
    }

    #pragma unroll
    for (int m = 0; m < 4; ++m) {
        int row = row0 + wr * 64 + m * 16 + lg * 4;
        #pragma unroll
        for (int n = 0; n < 4; ++n) {
            int col = col0 + wc * 64 + n * 16 + lr;
            float bcol = bias ? bias[col] : 0.0f;
            #pragma unroll
            for (int r = 0; r < 4; ++r) {
                float v = acc[m][n][r] + bcol;
                if (do_relu) v = fmaxf(v, 0.0f);
                if (OUT_F32) ((float*)outp)[(size_t)(row + r) * dout + col] = v;
                else         ((u16*)outp)[(size_t)(row + r) * dout + col] = f2b(v);
            }
        }
    }
}

// ---------------- fused layer-2 aggregation + classifier ----------------
// h3[node] = agg(z2)[node]*rinv + y2[node];  out = sigmoid(h3 . Wc + bc)
// z2: bf16 128-dim (256B rows); y2: f32 128-dim. One wave per node, 2 feats/lane.
__launch_bounds__(256)
__global__ void aggcls_kernel(const int* __restrict__ rowptr, const int* __restrict__ rowend,
                              const int* __restrict__ csr_src, const float* __restrict__ rinv,
                              const u16* __restrict__ z2, const float* __restrict__ y2,
                              const float* __restrict__ Wc, const float* __restrict__ bc,
                              float* __restrict__ out) {
    __shared__ float sW[128];
    int t = threadIdx.x;
    if (t < 128) sW[t] = Wc[t];
    __syncthreads();
    int node = blockIdx.x * 4 + (t >> 6);
    int lane = t & 63;
    if (node >= N_NODES) return;
    int beg = rowptr[node];
    int end = rowend[node];
    float a0 = 0.f, a1 = 0.f;
    int p = beg;
    for (; p + 3 < end; p += 4) {
        int s0 = csr_src[p], s1 = csr_src[p + 1], s2 = csr_src[p + 2], s3 = csr_src[p + 3];
        ushort2 v0 = *(const ushort2*)(z2 + (size_t)s0 * 128 + lane * 2);
        ushort2 v1 = *(const ushort2*)(z2 + (size_t)s1 * 128 + lane * 2);
        ushort2 v2 = *(const ushort2*)(z2 + (size_t)s2 * 128 + lane * 2);
        ushort2 v3 = *(const ushort2*)(z2 + (size_t)s3 * 128 + lane * 2);
        a0 += (b2f(v0.x) + b2f(v1.x)) + (b2f(v2.x) + b2f(v3.x));
        a1 += (b2f(v0.y) + b2f(v1.y)) + (b2f(v2.y) + b2f(v3.y));
    }
    for (; p < end; ++p) {
        int s0 = csr_src[p];
        ushort2 v0 = *(const ushort2*)(z2 + (size_t)s0 * 128 + lane * 2);
        a0 += b2f(v0.x); a1 += b2f(v0.y);
    }
    float r = rinv[node];
    float2 y = *(const float2*)(y2 + (size_t)node * 128 + lane * 2);
    float h0 = a0 * r + y.x;
    float h1 = a1 * r + y.y;
    float s = h0 * sW[lane * 2] + h1 * sW[lane * 2 + 1];
    #pragma unroll
    for (int off = 32; off; off >>= 1) s += __shfl_xor(s, off, 64);
    if (lane == 0) {
        float z = s + bc[0];
        out[node] = 1.0f / (1.0f + expf(-z));
    }
}

extern "C" void kernel_launch(void* const* d_in, const int* in_sizes, int n_in,
                              void* d_out, int out_size, void* d_ws, size_t ws_size,
                              hipStream_t stream) {
    const float* x   = (const float*)d_in[0];
    const int*   ei  = (const int*)d_in[1];
    const float* Wl0 = (const float*)d_in[2];
    const float* Wr0 = (const float*)d_in[3];
    const float* b0  = (const float*)d_in[4];
    const float* Wl1 = (const float*)d_in[5];
    const float* Wr1 = (const float*)d_in[6];
    const float* b1  = (const float*)d_in[7];
    const float* Wl2 = (const float*)d_in[8];
    const float* Wr2 = (const float*)d_in[9];
    const float* b2  = (const float*)d_in[10];
    const float* Wc  = (const float*)d_in[11];
    const float* bc  = (const float*)d_in[12];
    float* out = (float*)d_out;

    const int* src = ei;
    const int* dst = ei + N_EDGES;

    // ---- workspace layout ----
    int*   MT     = (int*)d_ws;                    // MT_PAD
    int*   MTs    = MT + MT_PAD;                   // MT_PAD
    int*   bsums  = MTs + MT_PAD;                  // 1024
    u32*   csrtmp = (u32*)(bsums + 1024);          // N_EDGES
    int*   csr    = (int*)(csrtmp + N_EDGES);      // N_EDGES
    int*   rowptr = csr + N_EDGES;                 // N_PAD
    int*   rowend = rowptr + N_PAD;                // N_PAD
    float* rinv   = (float*)(rowend + N_PAD);      // N_PAD
    u16*   xb     = (u16*)(rinv + N_PAD);          // N_PAD*256
    u16*   wb     = xb + (size_t)N_PAD * 256;      // weights
    u16*   bufA   = wb + 327680;                   // agg / z2
    u16*   bufB   = bufA + (size_t)N_PAD * 256;    // h1 / y2(f32)
    u16*   bufC   = bufB + (size_t)N_PAD * 256;    // h2

    u16* wl0 = wb;
    u16* wr0 = wl0 + 65536;
    u16* wl1 = wr0 + 65536;
    u16* wr1 = wl1 + 65536;
    u16* wl2 = wr1 + 65536;
    u16* wr2 = wl2 + 32768;

    // ---- conversions (bf16) ----
    cvt_kernel<<<(N_NODES * 64 + 255) / 256, 256, 0, stream>>>(x, xb, N_NODES * 64);
    cvt_kernel<<<64, 256, 0, stream>>>(Wl0, wl0, 16384);
    cvt_kernel<<<64, 256, 0, stream>>>(Wr0, wr0, 16384);
    cvt_kernel<<<64, 256, 0, stream>>>(Wl1, wl1, 16384);
    cvt_kernel<<<64, 256, 0, stream>>>(Wr1, wr1, 16384);
    cvt_kernel<<<32, 256, 0, stream>>>(Wl2, wl2, 8192);
    cvt_kernel<<<32, 256, 0, stream>>>(Wr2, wr2, 8192);

    // ---- CSR build ----
    const int scan_blocks = (MT_N + 255) / 256;    // 783
    p1_hist<<<NC, 256, 0, stream>>>(dst, MT);
    scan1_kernel<<<scan_blocks, 256, 0, stream>>>(MT, MTs, bsums, MT_N);
    scan_carry_kernel<<<1, 256, 0, stream>>>(bsums, scan_blocks);
    scan3_kernel<<<scan_blocks, 256, 0, stream>>>(MTs, bsums, MT_N);
    p2_partition<<<NC, 256, 0, stream>>>(src, dst, MTs, csrtmp);
    p3_csr<<<NB, 256, 0, stream>>>(MTs, csrtmp, csr, rowptr, rowend, rinv);

    const int Mblocks = (N_NODES + 127) / 128;     // 782
    dim3 g01(Mblocks, 2);
    dim3 g2(Mblocks, 1);
    const int agg_blocks = (N_NODES + 3) / 4;

    // ---- layer 0 ----
    agg_kernel<<<agg_blocks, 256, 0, stream>>>(rowptr, rowend, csr, rinv, xb, bufA);
    sage_gemm<false, true><<<g01, 256, 0, stream>>>(bufA, xb, wl0, wr0, b0, bufB, 256, 1);

    // ---- layer 1 ----
    agg_kernel<<<agg_blocks, 256, 0, stream>>>(rowptr, rowend, csr, rinv, bufB, bufA);
    sage_gemm<false, true><<<g01, 256, 0, stream>>>(bufA, bufB, wl1, wr1, b1, bufC, 256, 1);

    // ---- layer 2, projection-first (agg is linear) ----
    // z2 = h2 @ Wl2^T (bf16, no bias); y2 = h2 @ Wr2^T + b2 (f32)
    sage_gemm<false, false><<<g2, 256, 0, stream>>>(bufC, nullptr, wl2, nullptr, nullptr, bufA, 128, 0);
    sage_gemm<true,  false><<<g2, 256, 0, stream>>>(bufC, nullptr, wr2, nullptr, b2, bufB, 128, 0);
    // h3 = agg(z2)*rinv + y2, fused with classifier
    aggcls_kernel<<<agg_blocks, 256, 0, stream>>>(rowptr, rowend, csr, rinv,
                                                  bufA, (const float*)bufB, Wc, bc, out);
}

// Round 7
// 572.590 us; speedup vs baseline: 30.8058x; 1.0315x over previous
//
#include <hip/hip_runtime.h>
#include <math.h>

#define N_NODES 100000
#define N_PAD   100352
#define N_EDGES 1600000
#define DIN 256

// CSR bucket-partition parameters
#define NB 782        // buckets of 128 dst nodes
#define NC 256        // edge chunks
#define CHUNK 6250    // N_EDGES / NC exactly
#define MT_N (NB * NC)
#define MT_PAD 200448

typedef unsigned short u16;
typedef unsigned int u32;
typedef __attribute__((ext_vector_type(8))) short bf16x8;
typedef __attribute__((ext_vector_type(4))) float f32x4;

__device__ __forceinline__ float b2f(u16 u) {
    union { unsigned int i; float f; } c; c.i = ((unsigned int)u) << 16; return c.f;
}
__device__ __forceinline__ u16 f2b(float f) {
    union { float f; unsigned int i; } c; c.f = f;
    unsigned int x = c.i;
    return (u16)((x + 0x7fffu + ((x >> 16) & 1u)) >> 16);   // RNE
}

// async global->LDS, 16B per lane; lds base must be wave-uniform
__device__ __forceinline__ void gload_lds16(const u16* g, u16* lds_base) {
    __builtin_amdgcn_global_load_lds(
        (const __attribute__((address_space(1))) void*)g,
        (__attribute__((address_space(3))) void*)lds_base, 16, 0, 0);
}

// ---------------- f32 -> bf16 conversion ----------------
__global__ void cvt_kernel(const float* __restrict__ in, u16* __restrict__ out, int n4) {
    int i = blockIdx.x * blockDim.x + threadIdx.x;
    if (i < n4) {
        float4 v = ((const float4*)in)[i];
        ushort4 o;
        o.x = f2b(v.x); o.y = f2b(v.y); o.z = f2b(v.z); o.w = f2b(v.w);
        ((ushort4*)out)[i] = o;
    }
}

// ---------------- CSR build: atomic-free bucket partition ----------------
__launch_bounds__(256)
__global__ void p1_hist(const int* __restrict__ dst, int* __restrict__ MT) {
    __shared__ int bins[NB];
    const int c = blockIdx.x, tid = threadIdx.x;
    for (int b = tid; b < NB; b += 256) bins[b] = 0;
    __syncthreads();
    const int e0 = c * CHUNK;
    for (int e = e0 + tid; e < e0 + CHUNK; e += 256)
        atomicAdd(&bins[dst[e] >> 7], 1);
    __syncthreads();
    for (int b = tid; b < NB; b += 256) MT[b * NC + c] = bins[b];
}

__global__ void scan1_kernel(const int* __restrict__ in, int* __restrict__ excl,
                             int* __restrict__ blocksums, int n) {
    __shared__ int s[256];
    int tid = threadIdx.x;
    int i = blockIdx.x * 256 + tid;
    int v = (i < n) ? in[i] : 0;
    s[tid] = v;
    __syncthreads();
    for (int off = 1; off < 256; off <<= 1) {
        int t = (tid >= off) ? s[tid - off] : 0;
        __syncthreads();
        s[tid] += t;
        __syncthreads();
    }
    if (i < n) excl[i] = s[tid] - v;
    if (tid == 255) blocksums[blockIdx.x] = s[255];
}

__global__ void scan_carry_kernel(int* __restrict__ bsums, int nb) {
    __shared__ int s[256];
    int tid = threadIdx.x;
    int carry = 0;
    for (int base = 0; base < nb; base += 256) {
        int i = base + tid;
        int v = (i < nb) ? bsums[i] : 0;
        s[tid] = v;
        __syncthreads();
        for (int off = 1; off < 256; off <<= 1) {
            int t = (tid >= off) ? s[tid - off] : 0;
            __syncthreads();
            s[tid] += t;
            __syncthreads();
        }
        int incl = s[tid];
        int tot = s[255];
        if (i < nb) bsums[i] = incl - v + carry;
        carry += tot;
        __syncthreads();
    }
}

__global__ void scan3_kernel(int* __restrict__ excl, const int* __restrict__ blocksums, int n) {
    int i = blockIdx.x * 256 + threadIdx.x;
    if (i < n) excl[i] += blocksums[blockIdx.x];
}

__launch_bounds__(256)
__global__ void p2_partition(const int* __restrict__ src, const int* __restrict__ dst,
                             const int* __restrict__ scanMT, u32* __restrict__ csr_tmp) {
    __shared__ int cur[NB];
    const int c = blockIdx.x, tid = threadIdx.x;
    for (int b = tid; b < NB; b += 256) cur[b] = scanMT[b * NC + c];
    __syncthreads();
    const int e0 = c * CHUNK;
    for (int e = e0 + tid; e < e0 + CHUNK; e += 256) {
        int d = dst[e];
        int pos = atomicAdd(&cur[d >> 7], 1);   // LDS atomic
        csr_tmp[pos] = ((u32)(d & 127) << 25) | (u32)src[e];
    }
}

__launch_bounds__(256)
__global__ void p3_csr(const int* __restrict__ scanMT, const u32* __restrict__ csr_tmp,
                       int* __restrict__ csr, int* __restrict__ rowptr,
                       int* __restrict__ rowend, float* __restrict__ rinv) {
    __shared__ int cnt[128];
    __shared__ int excl[128];
    __shared__ int cur[128];
    const int b = blockIdx.x, tid = threadIdx.x;
    const int beg = scanMT[b * NC];
    const int end = (b == NB - 1) ? N_EDGES : scanMT[(b + 1) * NC];
    if (tid < 128) cnt[tid] = 0;
    __syncthreads();
    for (int e = beg + tid; e < end; e += 256)
        atomicAdd(&cnt[csr_tmp[e] >> 25], 1);
    __syncthreads();
    if (tid == 0) {
        int run = 0;
        for (int i = 0; i < 128; ++i) { excl[i] = run; run += cnt[i]; }
    }
    __syncthreads();
    if (tid < 128) cur[tid] = beg + excl[tid];
    __syncthreads();
    for (int e = beg + tid; e < end; e += 256) {
        u32 v = csr_tmp[e];
        int pos = atomicAdd(&cur[v >> 25], 1);  // LDS atomic
        csr[pos] = (int)(v & 0x1FFFFFFu);
    }
    if (tid < 128) {
        int node = b * 128 + tid;
        if (node < N_NODES) {
            int rp = beg + excl[tid];
            rowptr[node] = rp;
            rowend[node] = rp + cnt[tid];
            rinv[node]   = 1.0f / (float)max(cnt[tid], 1);
        }
    }
}

// ---------------- gather aggregation (bf16, f32 accum), 4-deep unroll ----------------
__launch_bounds__(256)
__global__ void agg_kernel(const int* __restrict__ rowptr, const int* __restrict__ rowend,
                           const int* __restrict__ csr_src, const float* __restrict__ rinv,
                           const u16* __restrict__ h, u16* __restrict__ agg) {
    int node = blockIdx.x * 4 + (threadIdx.x >> 6);
    int lane = threadIdx.x & 63;
    if (node >= N_NODES) return;
    int beg = rowptr[node];
    int end = rowend[node];
    float a0 = 0.f, a1 = 0.f, a2 = 0.f, a3 = 0.f;
    int p = beg;
    for (; p + 3 < end; p += 4) {
        int s0 = csr_src[p], s1 = csr_src[p + 1], s2 = csr_src[p + 2], s3 = csr_src[p + 3];
        ushort4 v0 = *(const ushort4*)(h + (size_t)s0 * DIN + lane * 4);
        ushort4 v1 = *(const ushort4*)(h + (size_t)s1 * DIN + lane * 4);
        ushort4 v2 = *(const ushort4*)(h + (size_t)s2 * DIN + lane * 4);
        ushort4 v3 = *(const ushort4*)(h + (size_t)s3 * DIN + lane * 4);
        a0 += (b2f(v0.x) + b2f(v1.x)) + (b2f(v2.x) + b2f(v3.x));
        a1 += (b2f(v0.y) + b2f(v1.y)) + (b2f(v2.y) + b2f(v3.y));
        a2 += (b2f(v0.z) + b2f(v1.z)) + (b2f(v2.z) + b2f(v3.z));
        a3 += (b2f(v0.w) + b2f(v1.w)) + (b2f(v2.w) + b2f(v3.w));
    }
    for (; p < end; ++p) {
        int s0 = csr_src[p];
        ushort4 v0 = *(const ushort4*)(h + (size_t)s0 * DIN + lane * 4);
        a0 += b2f(v0.x); a1 += b2f(v0.y); a2 += b2f(v0.z); a3 += b2f(v0.w);
    }
    float r = rinv[node];
    ushort4 o;
    o.x = f2b(a0 * r); o.y = f2b(a1 * r); o.z = f2b(a2 * r); o.w = f2b(a3 * r);
    *(ushort4*)(agg + (size_t)node * DIN + lane * 4) = o;
}

// ---------------- MFMA GEMM with global_load_lds staging ----------------
// LDS tiles linear [128][32] u16 (row stride 64B). Swizzle (both-sides, rule 21):
//   store: lds[row][16B-block a] holds g[row][a ^ (row&3)]
//   read:  g[row][lg] is at lds[row][lg ^ (row&3)]  -> 8 banks / 16-lane group (free)
// MODE 0: DUAL K=512, out = act([A0|A1]@[B0w|B1w]^T + bias), bf16 out.
// MODE 1: K=256, blockIdx.y==0: A0@B0w^T -> bf16 out0 (no bias)
//                blockIdx.y==1: A0@B1w^T + bias -> f32 out1
template <int MODE>
__launch_bounds__(256)
__global__ void sage_gemm(const u16* __restrict__ A0, const u16* __restrict__ A1,
                          const u16* __restrict__ B0w, const u16* __restrict__ B1w,
                          const float* __restrict__ bias, void* __restrict__ out0,
                          void* __restrict__ out1, int dout, int do_relu) {
    __shared__ u16 sA[128 * 32];
    __shared__ u16 sB[128 * 32];

    const int t    = threadIdx.x;
    const int row0 = blockIdx.x * 128;
    const int col0 = (MODE == 0) ? blockIdx.y * 128 : 0;
    const int w    = t >> 6, lane = t & 63;
    const int wr   = w >> 1, wc = w & 1;
    const int lr   = lane & 15, lg = lane >> 4;

    // staging geometry: wave w covers rows [w*32, w*32+32) of the tile,
    // 2 instrs of 16 rows; lane l -> row r0+(l>>2), src 16B-block (l&3)^((l>>2)&3)
    const int srow  = (lane >> 2);            // 0..15
    const int sblk  = (lane & 3) ^ (srow & 3);// swizzled source 16B-block
    const u16* Bsrc_all = (MODE == 1 && blockIdx.y == 1) ? B1w : B0w;

    f32x4 acc[4][4] = {};

    const int KTOT = (MODE == 0) ? 512 : 256;
    for (int kt = 0; kt < KTOT; kt += 32) {
        const u16* Asrc = (MODE == 0 && kt >= 256) ? A1 : A0;
        const u16* Bsrc = (MODE == 0) ? ((kt >= 256) ? B1w : B0w) : Bsrc_all;
        const int  kb   = (MODE == 0 && kt >= 256) ? kt - 256 : kt;
        #pragma unroll
        for (int i = 0; i < 2; ++i) {
            int row = w * 32 + i * 16 + srow;
            gload_lds16(Asrc + (size_t)(row0 + row) * DIN + kb + sblk * 8,
                        sA + w * 1024 + i * 512);
            gload_lds16(Bsrc + (size_t)(col0 + row) * DIN + kb + sblk * 8,
                        sB + w * 1024 + i * 512);
        }
        __syncthreads();

        bf16x8 af[4], bfr[4];
        #pragma unroll
        for (int m = 0; m < 4; ++m) {
            int row = wr * 64 + m * 16 + lr;
            af[m] = *(const bf16x8*)&sA[row * 32 + 8 * (lg ^ (lr & 3))];
        }
        #pragma unroll
        for (int n = 0; n < 4; ++n) {
            int row = wc * 64 + n * 16 + lr;
            bfr[n] = *(const bf16x8*)&sB[row * 32 + 8 * (lg ^ (lr & 3))];
        }
        #pragma unroll
        for (int m = 0; m < 4; ++m)
            #pragma unroll
            for (int n = 0; n < 4; ++n)
                acc[m][n] = __builtin_amdgcn_mfma_f32_16x16x32_bf16(af[m], bfr[n], acc[m][n], 0, 0, 0);
        __syncthreads();
    }

    const bool f32out = (MODE == 1) && (blockIdx.y == 1);
    const bool use_bias = (MODE == 0) || f32out;
    #pragma unroll
    for (int m = 0; m < 4; ++m) {
        int row = row0 + wr * 64 + m * 16 + lg * 4;
        #pragma unroll
        for (int n = 0; n < 4; ++n) {
            int col = col0 + wc * 64 + n * 16 + lr;
            float bcol = use_bias ? bias[col] : 0.0f;
            #pragma unroll
            for (int r = 0; r < 4; ++r) {
                float v = acc[m][n][r] + bcol;
                if (MODE == 0 && do_relu) v = fmaxf(v, 0.0f);
                if (f32out) ((float*)out1)[(size_t)(row + r) * dout + col] = v;
                else        ((u16*)out0)[(size_t)(row + r) * dout + col] = f2b(v);
            }
        }
    }
}

// ---------------- fused layer-2 aggregation + classifier ----------------
__launch_bounds__(256)
__global__ void aggcls_kernel(const int* __restrict__ rowptr, const int* __restrict__ rowend,
                              const int* __restrict__ csr_src, const float* __restrict__ rinv,
                              const u16* __restrict__ z2, const float* __restrict__ y2,
                              const float* __restrict__ Wc, const float* __restrict__ bc,
                              float* __restrict__ out) {
    __shared__ float sW[128];
    int t = threadIdx.x;
    if (t < 128) sW[t] = Wc[t];
    __syncthreads();
    int node = blockIdx.x * 4 + (t >> 6);
    int lane = t & 63;
    if (node >= N_NODES) return;
    int beg = rowptr[node];
    int end = rowend[node];
    float a0 = 0.f, a1 = 0.f;
    int p = beg;
    for (; p + 3 < end; p += 4) {
        int s0 = csr_src[p], s1 = csr_src[p + 1], s2 = csr_src[p + 2], s3 = csr_src[p + 3];
        ushort2 v0 = *(const ushort2*)(z2 + (size_t)s0 * 128 + lane * 2);
        ushort2 v1 = *(const ushort2*)(z2 + (size_t)s1 * 128 + lane * 2);
        ushort2 v2 = *(const ushort2*)(z2 + (size_t)s2 * 128 + lane * 2);
        ushort2 v3 = *(const ushort2*)(z2 + (size_t)s3 * 128 + lane * 2);
        a0 += (b2f(v0.x) + b2f(v1.x)) + (b2f(v2.x) + b2f(v3.x));
        a1 += (b2f(v0.y) + b2f(v1.y)) + (b2f(v2.y) + b2f(v3.y));
    }
    for (; p < end; ++p) {
        int s0 = csr_src[p];
        ushort2 v0 = *(const ushort2*)(z2 + (size_t)s0 * 128 + lane * 2);
        a0 += b2f(v0.x); a1 += b2f(v0.y);
    }
    float r = rinv[node];
    float2 y = *(const float2*)(y2 + (size_t)node * 128 + lane * 2);
    float h0 = a0 * r + y.x;
    float h1 = a1 * r + y.y;
    float s = h0 * sW[lane * 2] + h1 * sW[lane * 2 + 1];
    #pragma unroll
    for (int off = 32; off; off >>= 1) s += __shfl_xor(s, off, 64);
    if (lane == 0) {
        float z = s + bc[0];
        out[node] = 1.0f / (1.0f + expf(-z));
    }
}

extern "C" void kernel_launch(void* const* d_in, const int* in_sizes, int n_in,
                              void* d_out, int out_size, void* d_ws, size_t ws_size,
                              hipStream_t stream) {
    const float* x   = (const float*)d_in[0];
    const int*   ei  = (const int*)d_in[1];
    const float* Wl0 = (const float*)d_in[2];
    const float* Wr0 = (const float*)d_in[3];
    const float* b0  = (const float*)d_in[4];
    const float* Wl1 = (const float*)d_in[5];
    const float* Wr1 = (const float*)d_in[6];
    const float* b1  = (const float*)d_in[7];
    const float* Wl2 = (const float*)d_in[8];
    const float* Wr2 = (const float*)d_in[9];
    const float* b2  = (const float*)d_in[10];
    const float* Wc  = (const float*)d_in[11];
    const float* bc  = (const float*)d_in[12];
    float* out = (float*)d_out;

    const int* src = ei;
    const int* dst = ei + N_EDGES;

    // ---- workspace layout ----
    int*   MT     = (int*)d_ws;                    // MT_PAD
    int*   MTs    = MT + MT_PAD;                   // MT_PAD
    int*   bsums  = MTs + MT_PAD;                  // 1024
    u32*   csrtmp = (u32*)(bsums + 1024);          // N_EDGES
    int*   csr    = (int*)(csrtmp + N_EDGES);      // N_EDGES
    int*   rowptr = csr + N_EDGES;                 // N_PAD
    int*   rowend = rowptr + N_PAD;                // N_PAD
    float* rinv   = (float*)(rowend + N_PAD);      // N_PAD
    u16*   xb     = (u16*)(rinv + N_PAD);          // N_PAD*256
    u16*   wb     = xb + (size_t)N_PAD * 256;      // weights
    u16*   bufA   = wb + 327680;                   // agg / z2
    u16*   bufB   = bufA + (size_t)N_PAD * 256;    // h1 / y2(f32,128)
    u16*   bufC   = bufB + (size_t)N_PAD * 256;    // h2

    u16* wl0 = wb;
    u16* wr0 = wl0 + 65536;
    u16* wl1 = wr0 + 65536;
    u16* wr1 = wl1 + 65536;
    u16* wl2 = wr1 + 65536;
    u16* wr2 = wl2 + 32768;

    // ---- conversions (bf16) ----
    cvt_kernel<<<(N_NODES * 64 + 255) / 256, 256, 0, stream>>>(x, xb, N_NODES * 64);
    cvt_kernel<<<64, 256, 0, stream>>>(Wl0, wl0, 16384);
    cvt_kernel<<<64, 256, 0, stream>>>(Wr0, wr0, 16384);
    cvt_kernel<<<64, 256, 0, stream>>>(Wl1, wl1, 16384);
    cvt_kernel<<<64, 256, 0, stream>>>(Wr1, wr1, 16384);
    cvt_kernel<<<32, 256, 0, stream>>>(Wl2, wl2, 8192);
    cvt_kernel<<<32, 256, 0, stream>>>(Wr2, wr2, 8192);

    // ---- CSR build ----
    const int scan_blocks = (MT_N + 255) / 256;    // 783
    p1_hist<<<NC, 256, 0, stream>>>(dst, MT);
    scan1_kernel<<<scan_blocks, 256, 0, stream>>>(MT, MTs, bsums, MT_N);
    scan_carry_kernel<<<1, 256, 0, stream>>>(bsums, scan_blocks);
    scan3_kernel<<<scan_blocks, 256, 0, stream>>>(MTs, bsums, MT_N);
    p2_partition<<<NC, 256, 0, stream>>>(src, dst, MTs, csrtmp);
    p3_csr<<<NB, 256, 0, stream>>>(MTs, csrtmp, csr, rowptr, rowend, rinv);

    const int Mblocks = (N_NODES + 127) / 128;     // 782
    dim3 g01(Mblocks, 2);
    dim3 g2(Mblocks, 2);
    const int agg_blocks = (N_NODES + 3) / 4;

    // ---- layer 0 ----
    agg_kernel<<<agg_blocks, 256, 0, stream>>>(rowptr, rowend, csr, rinv, xb, bufA);
    sage_gemm<0><<<g01, 256, 0, stream>>>(bufA, xb, wl0, wr0, b0, bufB, nullptr, 256, 1);

    // ---- layer 1 ----
    agg_kernel<<<agg_blocks, 256, 0, stream>>>(rowptr, rowend, csr, rinv, bufB, bufA);
    sage_gemm<0><<<g01, 256, 0, stream>>>(bufA, bufB, wl1, wr1, b1, bufC, nullptr, 256, 1);

    // ---- layer 2, projection-first (agg is linear), one dispatch ----
    // y=0: z2 = h2 @ Wl2^T (bf16, no bias) -> bufA ; y=1: y2 = h2 @ Wr2^T + b2 (f32) -> bufB
    sage_gemm<1><<<g2, 256, 0, stream>>>(bufC, nullptr, wl2, wr2, b2, bufA, bufB, 128, 0);
    // h3 = agg(z2)*rinv + y2, fused with classifier
    aggcls_kernel<<<agg_blocks, 256, 0, stream>>>(rowptr, rowend, csr, rinv,
                                                  bufA, (const float*)bufB, Wc, bc, out);
}

// Round 8
// 540.093 us; speedup vs baseline: 32.6593x; 1.0602x over previous
//
#include <hip/hip_runtime.h>
#include <math.h>

#define N_NODES 100000
#define N_PAD   100352
#define N_EDGES 1600000
#define DIN 256

// CSR bucket-partition parameters
#define NB 782        // buckets of 128 dst nodes
#define NC 256        // edge chunks
#define CHUNK 6250    // N_EDGES / NC exactly
#define MT_N (NB * NC)
#define MT_PAD 200448

typedef unsigned short u16;
typedef unsigned int u32;
typedef __attribute__((ext_vector_type(8))) short bf16x8;
typedef __attribute__((ext_vector_type(8))) unsigned short us8;
typedef __attribute__((ext_vector_type(4))) float f32x4;

__device__ __forceinline__ float b2f(u16 u) {
    union { unsigned int i; float f; } c; c.i = ((unsigned int)u) << 16; return c.f;
}
__device__ __forceinline__ u16 f2b(float f) {
    union { float f; unsigned int i; } c; c.f = f;
    unsigned int x = c.i;
    return (u16)((x + 0x7fffu + ((x >> 16) & 1u)) >> 16);   // RNE
}

// async global->LDS, 16B per lane; lds base must be wave-uniform
__device__ __forceinline__ void gload_lds16(const u16* g, u16* lds_base) {
    __builtin_amdgcn_global_load_lds(
        (const __attribute__((address_space(1))) void*)g,
        (__attribute__((address_space(3))) void*)lds_base, 16, 0, 0);
}

// ---------------- f32 -> bf16 conversions ----------------
__global__ void cvt_kernel(const float* __restrict__ in, u16* __restrict__ out, int n4) {
    int i = blockIdx.x * blockDim.x + threadIdx.x;
    if (i < n4) {
        float4 v = ((const float4*)in)[i];
        ushort4 o;
        o.x = f2b(v.x); o.y = f2b(v.y); o.z = f2b(v.z); o.w = f2b(v.w);
        ((ushort4*)out)[i] = o;
    }
}

// all 6 weight matrices in one launch: blocks [0,64) Wl0, [64,128) Wr0,
// [128,192) Wl1, [192,256) Wr1, [256,288) Wl2, [288,320) Wr2
__global__ void cvtw_kernel(const float* __restrict__ Wl0, const float* __restrict__ Wr0,
                            const float* __restrict__ Wl1, const float* __restrict__ Wr1,
                            const float* __restrict__ Wl2, const float* __restrict__ Wr2,
                            u16* __restrict__ wl0, u16* __restrict__ wr0,
                            u16* __restrict__ wl1, u16* __restrict__ wr1,
                            u16* __restrict__ wl2, u16* __restrict__ wr2) {
    int b = blockIdx.x;
    const float* s; u16* d; int i;
    if (b < 64)       { s = Wl0; d = wl0; i = b * 256 + threadIdx.x; }
    else if (b < 128) { s = Wr0; d = wr0; i = (b - 64) * 256 + threadIdx.x; }
    else if (b < 192) { s = Wl1; d = wl1; i = (b - 128) * 256 + threadIdx.x; }
    else if (b < 256) { s = Wr1; d = wr1; i = (b - 192) * 256 + threadIdx.x; }
    else if (b < 288) { s = Wl2; d = wl2; i = (b - 256) * 256 + threadIdx.x; }
    else              { s = Wr2; d = wr2; i = (b - 288) * 256 + threadIdx.x; }
    float4 v = ((const float4*)s)[i];
    ushort4 o;
    o.x = f2b(v.x); o.y = f2b(v.y); o.z = f2b(v.z); o.w = f2b(v.w);
    ((ushort4*)d)[i] = o;
}

// ---------------- CSR build: atomic-free bucket partition ----------------
__launch_bounds__(256)
__global__ void p1_hist(const int* __restrict__ dst, int* __restrict__ MT) {
    __shared__ int bins[NB];
    const int c = blockIdx.x, tid = threadIdx.x;
    for (int b = tid; b < NB; b += 256) bins[b] = 0;
    __syncthreads();
    const int e0 = c * CHUNK;
    for (int e = e0 + tid; e < e0 + CHUNK; e += 256)
        atomicAdd(&bins[dst[e] >> 7], 1);
    __syncthreads();
    for (int b = tid; b < NB; b += 256) MT[b * NC + c] = bins[b];
}

__global__ void scan1_kernel(const int* __restrict__ in, int* __restrict__ excl,
                             int* __restrict__ blocksums, int n) {
    __shared__ int s[256];
    int tid = threadIdx.x;
    int i = blockIdx.x * 256 + tid;
    int v = (i < n) ? in[i] : 0;
    s[tid] = v;
    __syncthreads();
    for (int off = 1; off < 256; off <<= 1) {
        int t = (tid >= off) ? s[tid - off] : 0;
        __syncthreads();
        s[tid] += t;
        __syncthreads();
    }
    if (i < n) excl[i] = s[tid] - v;
    if (tid == 255) blocksums[blockIdx.x] = s[255];
}

__global__ void scan_carry_kernel(int* __restrict__ bsums, int nb) {
    __shared__ int s[256];
    int tid = threadIdx.x;
    int carry = 0;
    for (int base = 0; base < nb; base += 256) {
        int i = base + tid;
        int v = (i < nb) ? bsums[i] : 0;
        s[tid] = v;
        __syncthreads();
        for (int off = 1; off < 256; off <<= 1) {
            int t = (tid >= off) ? s[tid - off] : 0;
            __syncthreads();
            s[tid] += t;
            __syncthreads();
        }
        int incl = s[tid];
        int tot = s[255];
        if (i < nb) bsums[i] = incl - v + carry;
        carry += tot;
        __syncthreads();
    }
}

__global__ void scan3_kernel(int* __restrict__ excl, const int* __restrict__ blocksums, int n) {
    int i = blockIdx.x * 256 + threadIdx.x;
    if (i < n) excl[i] += blocksums[blockIdx.x];
}

__launch_bounds__(256)
__global__ void p2_partition(const int* __restrict__ src, const int* __restrict__ dst,
                             const int* __restrict__ scanMT, u32* __restrict__ csr_tmp) {
    __shared__ int cur[NB];
    const int c = blockIdx.x, tid = threadIdx.x;
    for (int b = tid; b < NB; b += 256) cur[b] = scanMT[b * NC + c];
    __syncthreads();
    const int e0 = c * CHUNK;
    for (int e = e0 + tid; e < e0 + CHUNK; e += 256) {
        int d = dst[e];
        int pos = atomicAdd(&cur[d >> 7], 1);   // LDS atomic
        csr_tmp[pos] = ((u32)(d & 127) << 25) | (u32)src[e];
    }
}

__launch_bounds__(256)
__global__ void p3_csr(const int* __restrict__ scanMT, const u32* __restrict__ csr_tmp,
                       int* __restrict__ csr, int* __restrict__ rowptr,
                       int* __restrict__ rowend, float* __restrict__ rinv) {
    __shared__ int cnt[128];
    __shared__ int excl[128];
    __shared__ int cur[128];
    const int b = blockIdx.x, tid = threadIdx.x;
    const int beg = scanMT[b * NC];
    const int end = (b == NB - 1) ? N_EDGES : scanMT[(b + 1) * NC];
    if (tid < 128) cnt[tid] = 0;
    __syncthreads();
    for (int e = beg + tid; e < end; e += 256)
        atomicAdd(&cnt[csr_tmp[e] >> 25], 1);
    __syncthreads();
    if (tid == 0) {
        int run = 0;
        for (int i = 0; i < 128; ++i) { excl[i] = run; run += cnt[i]; }
    }
    __syncthreads();
    if (tid < 128) cur[tid] = beg + excl[tid];
    __syncthreads();
    for (int e = beg + tid; e < end; e += 256) {
        u32 v = csr_tmp[e];
        int pos = atomicAdd(&cur[v >> 25], 1);  // LDS atomic
        csr[pos] = (int)(v & 0x1FFFFFFu);
    }
    if (tid < 128) {
        int node = b * 128 + tid;
        if (node < N_NODES) {
            int rp = beg + excl[tid];
            rowptr[node] = rp;
            rowend[node] = rp + cnt[tid];
            rinv[node]   = 1.0f / (float)max(cnt[tid], 1);
        }
    }
}

// ---------------- gather aggregation: 32 lanes/node, 16B/lane, unroll 4 ----------------
__launch_bounds__(256)
__global__ void agg_kernel(const int* __restrict__ rowptr, const int* __restrict__ rowend,
                           const int* __restrict__ csr_src, const float* __restrict__ rinv,
                           const u16* __restrict__ h, u16* __restrict__ agg) {
    int node = blockIdx.x * 8 + (threadIdx.x >> 5);
    int lane = threadIdx.x & 31;
    if (node >= N_NODES) return;
    int beg = rowptr[node];
    int end = rowend[node];
    const u16* hl = h + lane * 8;
    float a[8] = {};
    int p = beg;
    for (; p + 3 < end; p += 4) {
        int s0 = csr_src[p], s1 = csr_src[p + 1], s2 = csr_src[p + 2], s3 = csr_src[p + 3];
        us8 v0 = *(const us8*)(hl + (size_t)s0 * DIN);
        us8 v1 = *(const us8*)(hl + (size_t)s1 * DIN);
        us8 v2 = *(const us8*)(hl + (size_t)s2 * DIN);
        us8 v3 = *(const us8*)(hl + (size_t)s3 * DIN);
        #pragma unroll
        for (int j = 0; j < 8; ++j)
            a[j] += (b2f(v0[j]) + b2f(v1[j])) + (b2f(v2[j]) + b2f(v3[j]));
    }
    for (; p < end; ++p) {
        int s0 = csr_src[p];
        us8 v0 = *(const us8*)(hl + (size_t)s0 * DIN);
        #pragma unroll
        for (int j = 0; j < 8; ++j) a[j] += b2f(v0[j]);
    }
    float r = rinv[node];
    us8 o;
    #pragma unroll
    for (int j = 0; j < 8; ++j) o[j] = f2b(a[j] * r);
    *(us8*)(agg + (size_t)node * DIN + lane * 8) = o;
}

// ---------------- MFMA GEMM: 2-phase double-buffered global_load_lds ----------------
// LDS tiles linear [128][32] u16. Both-sides XOR-16 swizzle (rule 21):
//   store: lds[row][16B-blk a] holds g[row][a ^ (row&3)]; read applies same XOR.
// MODE 0: DUAL K=512, out = act([A0|A1]@[B0w|B1w]^T + bias), bf16 out.
// MODE 1: K=256, y==0: A0@B0w^T -> bf16 out0 (no bias); y==1: A0@B1w^T+bias -> f32 out1
template <int MODE>
__launch_bounds__(256)
__global__ void sage_gemm(const u16* __restrict__ A0, const u16* __restrict__ A1,
                          const u16* __restrict__ B0w, const u16* __restrict__ B1w,
                          const float* __restrict__ bias, void* __restrict__ out0,
                          void* __restrict__ out1, int dout, int do_relu) {
    __shared__ u16 sA[2][128 * 32];
    __shared__ u16 sB[2][128 * 32];

    const int t    = threadIdx.x;
    const int row0 = blockIdx.x * 128;
    const int col0 = (MODE == 0) ? blockIdx.y * 128 : 0;
    const int w    = t >> 6, lane = t & 63;
    const int wr   = w >> 1, wc = w & 1;
    const int lr   = lane & 15, lg = lane >> 4;
    const int srow = lane >> 2;
    const int sblk = (lane & 3) ^ (srow & 3);
    const u16* Bsrc_all = (MODE == 1 && blockIdx.y == 1) ? B1w : B0w;

    f32x4 acc[4][4] = {};
    const int NT = (MODE == 0) ? 16 : 8;

    auto stage = [&](int buf, int tk) {
        const int kt = tk * 32;
        const u16* Asrc = (MODE == 0 && kt >= 256) ? A1 : A0;
        const u16* Bsrc = (MODE == 0) ? ((kt >= 256) ? B1w : B0w) : Bsrc_all;
        const int  kb   = (MODE == 0 && kt >= 256) ? kt - 256 : kt;
        #pragma unroll
        for (int i = 0; i < 2; ++i) {
            int row = w * 32 + i * 16 + srow;
            gload_lds16(Asrc + (size_t)(row0 + row) * DIN + kb + sblk * 8,
                        &sA[buf][w * 1024 + i * 512]);
            gload_lds16(Bsrc + (size_t)(col0 + row) * DIN + kb + sblk * 8,
                        &sB[buf][w * 1024 + i * 512]);
        }
    };

    stage(0, 0);
    __syncthreads();                        // drains vmcnt: buf0 ready
    for (int tk = 0; tk < NT; ++tk) {
        const int cur = tk & 1;
        if (tk + 1 < NT) stage(cur ^ 1, tk + 1);   // overlaps with MFMA below
        bf16x8 af[4], bfr[4];
        #pragma unroll
        for (int m = 0; m < 4; ++m) {
            int row = wr * 64 + m * 16 + lr;
            af[m] = *(const bf16x8*)&sA[cur][row * 32 + 8 * (lg ^ (lr & 3))];
        }
        #pragma unroll
        for (int n = 0; n < 4; ++n) {
            int row = wc * 64 + n * 16 + lr;
            bfr[n] = *(const bf16x8*)&sB[cur][row * 32 + 8 * (lg ^ (lr & 3))];
        }
        #pragma unroll
        for (int m = 0; m < 4; ++m)
            #pragma unroll
            for (int n = 0; n < 4; ++n)
                acc[m][n] = __builtin_amdgcn_mfma_f32_16x16x32_bf16(af[m], bfr[n], acc[m][n], 0, 0, 0);
        __syncthreads();                    // drains next-tile loads; protects overwrite
    }

    const bool f32out = (MODE == 1) && (blockIdx.y == 1);
    const bool use_bias = (MODE == 0) || f32out;
    #pragma unroll
    for (int m = 0; m < 4; ++m) {
        int row = row0 + wr * 64 + m * 16 + lg * 4;
        #pragma unroll
        for (int n = 0; n < 4; ++n) {
            int col = col0 + wc * 64 + n * 16 + lr;
            float bcol = use_bias ? bias[col] : 0.0f;
            #pragma unroll
            for (int r = 0; r < 4; ++r) {
                float v = acc[m][n][r] + bcol;
                if (MODE == 0 && do_relu) v = fmaxf(v, 0.0f);
                if (f32out) ((float*)out1)[(size_t)(row + r) * dout + col] = v;
                else        ((u16*)out0)[(size_t)(row + r) * dout + col] = f2b(v);
            }
        }
    }
}

// ---------------- fused layer-2 agg + classifier: 16 lanes/node, 16B/lane ----------------
__launch_bounds__(256)
__global__ void aggcls_kernel(const int* __restrict__ rowptr, const int* __restrict__ rowend,
                              const int* __restrict__ csr_src, const float* __restrict__ rinv,
                              const u16* __restrict__ z2, const float* __restrict__ y2,
                              const float* __restrict__ Wc, const float* __restrict__ bc,
                              float* __restrict__ out) {
    __shared__ float sW[128];
    int t = threadIdx.x;
    if (t < 128) sW[t] = Wc[t];
    __syncthreads();
    int node = blockIdx.x * 16 + (t >> 4);
    int lane = t & 15;
    if (node >= N_NODES) return;
    int beg = rowptr[node];
    int end = rowend[node];
    const u16* zl = z2 + lane * 8;
    float a[8] = {};
    int p = beg;
    for (; p + 3 < end; p += 4) {
        int s0 = csr_src[p], s1 = csr_src[p + 1], s2 = csr_src[p + 2], s3 = csr_src[p + 3];
        us8 v0 = *(const us8*)(zl + (size_t)s0 * 128);
        us8 v1 = *(const us8*)(zl + (size_t)s1 * 128);
        us8 v2 = *(const us8*)(zl + (size_t)s2 * 128);
        us8 v3 = *(const us8*)(zl + (size_t)s3 * 128);
        #pragma unroll
        for (int j = 0; j < 8; ++j)
            a[j] += (b2f(v0[j]) + b2f(v1[j])) + (b2f(v2[j]) + b2f(v3[j]));
    }
    for (; p < end; ++p) {
        int s0 = csr_src[p];
        us8 v0 = *(const us8*)(zl + (size_t)s0 * 128);
        #pragma unroll
        for (int j = 0; j < 8; ++j) a[j] += b2f(v0[j]);
    }
    float r = rinv[node];
    float4 ylo = *(const float4*)(y2 + (size_t)node * 128 + lane * 8);
    float4 yhi = *(const float4*)(y2 + (size_t)node * 128 + lane * 8 + 4);
    float yv[8] = { ylo.x, ylo.y, ylo.z, ylo.w, yhi.x, yhi.y, yhi.z, yhi.w };
    float s = 0.f;
    #pragma unroll
    for (int j = 0; j < 8; ++j)
        s += (a[j] * r + yv[j]) * sW[lane * 8 + j];
    #pragma unroll
    for (int off = 8; off; off >>= 1) s += __shfl_xor(s, off, 16);
    if (lane == 0) {
        float z = s + bc[0];
        out[node] = 1.0f / (1.0f + expf(-z));
    }
}

extern "C" void kernel_launch(void* const* d_in, const int* in_sizes, int n_in,
                              void* d_out, int out_size, void* d_ws, size_t ws_size,
                              hipStream_t stream) {
    const float* x   = (const float*)d_in[0];
    const int*   ei  = (const int*)d_in[1];
    const float* Wl0 = (const float*)d_in[2];
    const float* Wr0 = (const float*)d_in[3];
    const float* b0  = (const float*)d_in[4];
    const float* Wl1 = (const float*)d_in[5];
    const float* Wr1 = (const float*)d_in[6];
    const float* b1  = (const float*)d_in[7];
    const float* Wl2 = (const float*)d_in[8];
    const float* Wr2 = (const float*)d_in[9];
    const float* b2  = (const float*)d_in[10];
    const float* Wc  = (const float*)d_in[11];
    const float* bc  = (const float*)d_in[12];
    float* out = (float*)d_out;

    const int* src = ei;
    const int* dst = ei + N_EDGES;

    // ---- workspace layout ----
    int*   MT     = (int*)d_ws;                    // MT_PAD
    int*   MTs    = MT + MT_PAD;                   // MT_PAD
    int*   bsums  = MTs + MT_PAD;                  // 1024
    u32*   csrtmp = (u32*)(bsums + 1024);          // N_EDGES
    int*   csr    = (int*)(csrtmp + N_EDGES);      // N_EDGES
    int*   rowptr = csr + N_EDGES;                 // N_PAD
    int*   rowend = rowptr + N_PAD;                // N_PAD
    float* rinv   = (float*)(rowend + N_PAD);      // N_PAD
    u16*   xb     = (u16*)(rinv + N_PAD);          // N_PAD*256
    u16*   wb     = xb + (size_t)N_PAD * 256;      // weights
    u16*   bufA   = wb + 327680;                   // agg / z2
    u16*   bufB   = bufA + (size_t)N_PAD * 256;    // h1 / y2(f32,128)
    u16*   bufC   = bufB + (size_t)N_PAD * 256;    // h2

    u16* wl0 = wb;
    u16* wr0 = wl0 + 65536;
    u16* wl1 = wr0 + 65536;
    u16* wr1 = wl1 + 65536;
    u16* wl2 = wr1 + 65536;
    u16* wr2 = wl2 + 32768;

    // ---- conversions (bf16) ----
    cvt_kernel<<<(N_NODES * 64 + 255) / 256, 256, 0, stream>>>(x, xb, N_NODES * 64);
    cvtw_kernel<<<320, 256, 0, stream>>>(Wl0, Wr0, Wl1, Wr1, Wl2, Wr2,
                                         wl0, wr0, wl1, wr1, wl2, wr2);

    // ---- CSR build ----
    const int scan_blocks = (MT_N + 255) / 256;    // 783
    p1_hist<<<NC, 256, 0, stream>>>(dst, MT);
    scan1_kernel<<<scan_blocks, 256, 0, stream>>>(MT, MTs, bsums, MT_N);
    scan_carry_kernel<<<1, 256, 0, stream>>>(bsums, scan_blocks);
    scan3_kernel<<<scan_blocks, 256, 0, stream>>>(MTs, bsums, MT_N);
    p2_partition<<<NC, 256, 0, stream>>>(src, dst, MTs, csrtmp);
    p3_csr<<<NB, 256, 0, stream>>>(MTs, csrtmp, csr, rowptr, rowend, rinv);

    const int Mblocks = (N_NODES + 127) / 128;     // 782
    dim3 g01(Mblocks, 2);
    dim3 g2(Mblocks, 2);
    const int agg_blocks = (N_NODES + 7) / 8;      // 12500
    const int aggcls_blocks = (N_NODES + 15) / 16; // 6250

    // ---- layer 0 ----
    agg_kernel<<<agg_blocks, 256, 0, stream>>>(rowptr, rowend, csr, rinv, xb, bufA);
    sage_gemm<0><<<g01, 256, 0, stream>>>(bufA, xb, wl0, wr0, b0, bufB, nullptr, 256, 1);

    // ---- layer 1 ----
    agg_kernel<<<agg_blocks, 256, 0, stream>>>(rowptr, rowend, csr, rinv, bufB, bufA);
    sage_gemm<0><<<g01, 256, 0, stream>>>(bufA, bufB, wl1, wr1, b1, bufC, nullptr, 256, 1);

    // ---- layer 2, projection-first (agg is linear), one dispatch ----
    sage_gemm<1><<<g2, 256, 0, stream>>>(bufC, nullptr, wl2, wr2, b2, bufA, bufB, 128, 0);
    // h3 = agg(z2)*rinv + y2, fused with classifier
    aggcls_kernel<<<aggcls_blocks, 256, 0, stream>>>(rowptr, rowend, csr, rinv,
                                                     bufA, (const float*)bufB, Wc, bc, out);
}

// Round 9
// 435.359 us; speedup vs baseline: 40.5161x; 1.2406x over previous
//
#include <hip/hip_runtime.h>
#include <math.h>

#define N_NODES 100000
#define N_PAD   100352
#define N_EDGES 1600000
#define DIN 256

// CSR bucket-partition parameters
#define NB 782        // buckets of 128 dst nodes
#define NC 256        // edge chunks
#define CHUNK 6250    // N_EDGES / NC exactly
#define MT_N (NB * NC)
#define MT_PAD 200448

typedef unsigned short u16;
typedef unsigned char u8;
typedef unsigned int u32;
typedef __attribute__((ext_vector_type(8))) short bf16x8;
typedef __attribute__((ext_vector_type(8))) unsigned short us8;
typedef __attribute__((ext_vector_type(4))) float f32x4;
typedef __attribute__((ext_vector_type(2))) float f32x2;

__device__ __forceinline__ float b2f(u16 u) {
    union { unsigned int i; float f; } c; c.i = ((unsigned int)u) << 16; return c.f;
}
__device__ __forceinline__ u16 f2b(float f) {
    union { float f; unsigned int i; } c; c.f = f;
    unsigned int x = c.i;
    return (u16)((x + 0x7fffu + ((x >> 16) & 1u)) >> 16);   // RNE
}
// hardware fp8 e4m3 (OCP on gfx950) encode/decode — both sides HW, so consistent
__device__ __forceinline__ u8 f32_to_fp8(float v) {
    return (u8)(__builtin_amdgcn_cvt_pk_fp8_f32(v, 0.0f, 0, false) & 0xff);
}
__device__ __forceinline__ void accum16(float* a, uint4 v) {  // 16 fp8 -> += 16 f32
    unsigned int w[4] = { v.x, v.y, v.z, v.w };
    #pragma unroll
    for (int q = 0; q < 4; ++q) {
        f32x2 lo = __builtin_amdgcn_cvt_pk_f32_fp8(w[q], false);
        f32x2 hi = __builtin_amdgcn_cvt_pk_f32_fp8(w[q], true);
        a[q * 4 + 0] += lo[0]; a[q * 4 + 1] += lo[1];
        a[q * 4 + 2] += hi[0]; a[q * 4 + 3] += hi[1];
    }
}
__device__ __forceinline__ void accum8(float* a, uint2 v) {   // 8 fp8 -> += 8 f32
    unsigned int w[2] = { v.x, v.y };
    #pragma unroll
    for (int q = 0; q < 2; ++q) {
        f32x2 lo = __builtin_amdgcn_cvt_pk_f32_fp8(w[q], false);
        f32x2 hi = __builtin_amdgcn_cvt_pk_f32_fp8(w[q], true);
        a[q * 4 + 0] += lo[0]; a[q * 4 + 1] += lo[1];
        a[q * 4 + 2] += hi[0]; a[q * 4 + 3] += hi[1];
    }
}

// async global->LDS, 16B per lane; lds base must be wave-uniform
__device__ __forceinline__ void gload_lds16(const u16* g, u16* lds_base) {
    __builtin_amdgcn_global_load_lds(
        (const __attribute__((address_space(1))) void*)g,
        (__attribute__((address_space(3))) void*)lds_base, 16, 0, 0);
}

// ---------------- f32 -> bf16 + fp8 conversion (x) ----------------
__global__ void cvt_kernel(const float* __restrict__ in, u16* __restrict__ outb,
                           u8* __restrict__ out8, int n4) {
    int i = blockIdx.x * blockDim.x + threadIdx.x;
    if (i < n4) {
        float4 v = ((const float4*)in)[i];
        ushort4 o;
        o.x = f2b(v.x); o.y = f2b(v.y); o.z = f2b(v.z); o.w = f2b(v.w);
        ((ushort4*)outb)[i] = o;
        u32 r = __builtin_amdgcn_cvt_pk_fp8_f32(v.x, v.y, 0, false);
        r = __builtin_amdgcn_cvt_pk_fp8_f32(v.z, v.w, r, true);
        ((u32*)out8)[i] = r;
    }
}

// all 6 weight matrices in one launch
__global__ void cvtw_kernel(const float* __restrict__ Wl0, const float* __restrict__ Wr0,
                            const float* __restrict__ Wl1, const float* __restrict__ Wr1,
                            const float* __restrict__ Wl2, const float* __restrict__ Wr2,
                            u16* __restrict__ wl0, u16* __restrict__ wr0,
                            u16* __restrict__ wl1, u16* __restrict__ wr1,
                            u16* __restrict__ wl2, u16* __restrict__ wr2) {
    int b = blockIdx.x;
    const float* s; u16* d; int i;
    if (b < 64)       { s = Wl0; d = wl0; i = b * 256 + threadIdx.x; }
    else if (b < 128) { s = Wr0; d = wr0; i = (b - 64) * 256 + threadIdx.x; }
    else if (b < 192) { s = Wl1; d = wl1; i = (b - 128) * 256 + threadIdx.x; }
    else if (b < 256) { s = Wr1; d = wr1; i = (b - 192) * 256 + threadIdx.x; }
    else if (b < 288) { s = Wl2; d = wl2; i = (b - 256) * 256 + threadIdx.x; }
    else              { s = Wr2; d = wr2; i = (b - 288) * 256 + threadIdx.x; }
    float4 v = ((const float4*)s)[i];
    ushort4 o;
    o.x = f2b(v.x); o.y = f2b(v.y); o.z = f2b(v.z); o.w = f2b(v.w);
    ((ushort4*)d)[i] = o;
}

// ---------------- CSR build: atomic-free bucket partition ----------------
__launch_bounds__(256)
__global__ void p1_hist(const int* __restrict__ dst, int* __restrict__ MT) {
    __shared__ int bins[NB];
    const int c = blockIdx.x, tid = threadIdx.x;
    for (int b = tid; b < NB; b += 256) bins[b] = 0;
    __syncthreads();
    const int e0 = c * CHUNK;
    for (int e = e0 + tid; e < e0 + CHUNK; e += 256)
        atomicAdd(&bins[dst[e] >> 7], 1);
    __syncthreads();
    for (int b = tid; b < NB; b += 256) MT[b * NC + c] = bins[b];
}

__global__ void scan1_kernel(const int* __restrict__ in, int* __restrict__ excl,
                             int* __restrict__ blocksums, int n) {
    __shared__ int s[256];
    int tid = threadIdx.x;
    int i = blockIdx.x * 256 + tid;
    int v = (i < n) ? in[i] : 0;
    s[tid] = v;
    __syncthreads();
    for (int off = 1; off < 256; off <<= 1) {
        int t = (tid >= off) ? s[tid - off] : 0;
        __syncthreads();
        s[tid] += t;
        __syncthreads();
    }
    if (i < n) excl[i] = s[tid] - v;
    if (tid == 255) blocksums[blockIdx.x] = s[255];
}

__global__ void scan_carry_kernel(int* __restrict__ bsums, int nb) {
    __shared__ int s[256];
    int tid = threadIdx.x;
    int carry = 0;
    for (int base = 0; base < nb; base += 256) {
        int i = base + tid;
        int v = (i < nb) ? bsums[i] : 0;
        s[tid] = v;
        __syncthreads();
        for (int off = 1; off < 256; off <<= 1) {
            int t = (tid >= off) ? s[tid - off] : 0;
            __syncthreads();
            s[tid] += t;
            __syncthreads();
        }
        int incl = s[tid];
        int tot = s[255];
        if (i < nb) bsums[i] = incl - v + carry;
        carry += tot;
        __syncthreads();
    }
}

__global__ void scan3_kernel(int* __restrict__ excl, const int* __restrict__ blocksums, int n) {
    int i = blockIdx.x * 256 + threadIdx.x;
    if (i < n) excl[i] += blocksums[blockIdx.x];
}

__launch_bounds__(256)
__global__ void p2_partition(const int* __restrict__ src, const int* __restrict__ dst,
                             const int* __restrict__ scanMT, u32* __restrict__ csr_tmp) {
    __shared__ int cur[NB];
    const int c = blockIdx.x, tid = threadIdx.x;
    for (int b = tid; b < NB; b += 256) cur[b] = scanMT[b * NC + c];
    __syncthreads();
    const int e0 = c * CHUNK;
    for (int e = e0 + tid; e < e0 + CHUNK; e += 256) {
        int d = dst[e];
        int pos = atomicAdd(&cur[d >> 7], 1);   // LDS atomic
        csr_tmp[pos] = ((u32)(d & 127) << 25) | (u32)src[e];
    }
}

__launch_bounds__(256)
__global__ void p3_csr(const int* __restrict__ scanMT, const u32* __restrict__ csr_tmp,
                       int* __restrict__ csr, int* __restrict__ rowptr,
                       int* __restrict__ rowend, float* __restrict__ rinv) {
    __shared__ int cnt[128];
    __shared__ int excl[128];
    __shared__ int cur[128];
    const int b = blockIdx.x, tid = threadIdx.x;
    const int beg = scanMT[b * NC];
    const int end = (b == NB - 1) ? N_EDGES : scanMT[(b + 1) * NC];
    if (tid < 128) cnt[tid] = 0;
    __syncthreads();
    for (int e = beg + tid; e < end; e += 256)
        atomicAdd(&cnt[csr_tmp[e] >> 25], 1);
    __syncthreads();
    if (tid == 0) {
        int run = 0;
        for (int i = 0; i < 128; ++i) { excl[i] = run; run += cnt[i]; }
    }
    __syncthreads();
    if (tid < 128) cur[tid] = beg + excl[tid];
    __syncthreads();
    for (int e = beg + tid; e < end; e += 256) {
        u32 v = csr_tmp[e];
        int pos = atomicAdd(&cur[v >> 25], 1);  // LDS atomic
        csr[pos] = (int)(v & 0x1FFFFFFu);
    }
    if (tid < 128) {
        int node = b * 128 + tid;
        if (node < N_NODES) {
            int rp = beg + excl[tid];
            rowptr[node] = rp;
            rowend[node] = rp + cnt[tid];
            rinv[node]   = 1.0f / (float)max(cnt[tid], 1);
        }
    }
}

// ---------------- gather aggregation: fp8 rows (256B), 16 lanes/node ----------------
__launch_bounds__(256)
__global__ void agg_kernel(const int* __restrict__ rowptr, const int* __restrict__ rowend,
                           const int* __restrict__ csr_src, const float* __restrict__ rinv,
                           const u8* __restrict__ h8, u16* __restrict__ agg) {
    int node = blockIdx.x * 16 + (threadIdx.x >> 4);
    int lane = threadIdx.x & 15;
    if (node >= N_NODES) return;
    int beg = rowptr[node];
    int end = rowend[node];
    const u8* hl = h8 + lane * 16;
    float a[16] = {};
    int p = beg;
    for (; p + 3 < end; p += 4) {
        int s0 = csr_src[p], s1 = csr_src[p + 1], s2 = csr_src[p + 2], s3 = csr_src[p + 3];
        uint4 v0 = *(const uint4*)(hl + (size_t)s0 * 256);
        uint4 v1 = *(const uint4*)(hl + (size_t)s1 * 256);
        uint4 v2 = *(const uint4*)(hl + (size_t)s2 * 256);
        uint4 v3 = *(const uint4*)(hl + (size_t)s3 * 256);
        accum16(a, v0); accum16(a, v1); accum16(a, v2); accum16(a, v3);
    }
    for (; p < end; ++p) {
        uint4 v0 = *(const uint4*)(hl + (size_t)csr_src[p] * 256);
        accum16(a, v0);
    }
    float r = rinv[node];
    us8 o0, o1;
    #pragma unroll
    for (int j = 0; j < 8; ++j) { o0[j] = f2b(a[j] * r); o1[j] = f2b(a[8 + j] * r); }
    u16* d = agg + (size_t)node * DIN + lane * 16;
    *(us8*)d = o0;
    *(us8*)(d + 8) = o1;
}

// ---------------- MFMA GEMM: 2-phase double-buffered global_load_lds ----------------
// LDS tiles linear [128][32] u16, both-sides XOR-16 swizzle (rule 21).
// MODE 0: DUAL K=512, out = act([A0|A1]@[B0w|B1w]^T + bias) -> bf16 out0 (+ fp8 out8 if set)
// MODE 1: K=256: y==0: A0@B0w^T -> fp8 out8 (no bias); y==1: A0@B1w^T + bias -> f32 out1
template <int MODE>
__launch_bounds__(256)
__global__ void sage_gemm(const u16* __restrict__ A0, const u16* __restrict__ A1,
                          const u16* __restrict__ B0w, const u16* __restrict__ B1w,
                          const float* __restrict__ bias, void* __restrict__ out0,
                          void* __restrict__ out1, u8* __restrict__ out8,
                          int dout, int do_relu) {
    __shared__ u16 sA[2][128 * 32];
    __shared__ u16 sB[2][128 * 32];

    const int t    = threadIdx.x;
    const int row0 = blockIdx.x * 128;
    const int col0 = (MODE == 0) ? blockIdx.y * 128 : 0;
    const int w    = t >> 6, lane = t & 63;
    const int wr   = w >> 1, wc = w & 1;
    const int lr   = lane & 15, lg = lane >> 4;
    const int srow = lane >> 2;
    const int sblk = (lane & 3) ^ (srow & 3);
    const u16* Bsrc_all = (MODE == 1 && blockIdx.y == 1) ? B1w : B0w;

    f32x4 acc[4][4] = {};
    const int NT = (MODE == 0) ? 16 : 8;

    auto stage = [&](int buf, int tk) {
        const int kt = tk * 32;
        const u16* Asrc = (MODE == 0 && kt >= 256) ? A1 : A0;
        const u16* Bsrc = (MODE == 0) ? ((kt >= 256) ? B1w : B0w) : Bsrc_all;
        const int  kb   = (MODE == 0 && kt >= 256) ? kt - 256 : kt;
        #pragma unroll
        for (int i = 0; i < 2; ++i) {
            int row = w * 32 + i * 16 + srow;
            gload_lds16(Asrc + (size_t)(row0 + row) * DIN + kb + sblk * 8,
                        &sA[buf][w * 1024 + i * 512]);
            gload_lds16(Bsrc + (size_t)(col0 + row) * DIN + kb + sblk * 8,
                        &sB[buf][w * 1024 + i * 512]);
        }
    };

    stage(0, 0);
    __syncthreads();
    for (int tk = 0; tk < NT; ++tk) {
        const int cur = tk & 1;
        if (tk + 1 < NT) stage(cur ^ 1, tk + 1);
        bf16x8 af[4], bfr[4];
        #pragma unroll
        for (int m = 0; m < 4; ++m) {
            int row = wr * 64 + m * 16 + lr;
            af[m] = *(const bf16x8*)&sA[cur][row * 32 + 8 * (lg ^ (lr & 3))];
        }
        #pragma unroll
        for (int n = 0; n < 4; ++n) {
            int row = wc * 64 + n * 16 + lr;
            bfr[n] = *(const bf16x8*)&sB[cur][row * 32 + 8 * (lg ^ (lr & 3))];
        }
        #pragma unroll
        for (int m = 0; m < 4; ++m)
            #pragma unroll
            for (int n = 0; n < 4; ++n)
                acc[m][n] = __builtin_amdgcn_mfma_f32_16x16x32_bf16(af[m], bfr[n], acc[m][n], 0, 0, 0);
        __syncthreads();
    }

    const bool f32out = (MODE == 1) && (blockIdx.y == 1);
    #pragma unroll
    for (int m = 0; m < 4; ++m) {
        int row = row0 + wr * 64 + m * 16 + lg * 4;
        #pragma unroll
        for (int n = 0; n < 4; ++n) {
            int col = col0 + wc * 64 + n * 16 + lr;
            #pragma unroll
            for (int r = 0; r < 4; ++r) {
                float v = acc[m][n][r];
                if (MODE == 0) {
                    v += bias[col];
                    if (do_relu) v = fmaxf(v, 0.0f);
                    ((u16*)out0)[(size_t)(row + r) * dout + col] = f2b(v);
                    if (out8) out8[(size_t)(row + r) * dout + col] = f32_to_fp8(v);
                } else if (f32out) {
                    v += bias[col];
                    ((float*)out1)[(size_t)(row + r) * dout + col] = v;
                } else {
                    out8[(size_t)(row + r) * dout + col] = f32_to_fp8(v);
                }
            }
        }
    }
}

// ---------------- fused layer-2 agg + classifier: fp8 z2 rows (128B) ----------------
__launch_bounds__(256)
__global__ void aggcls_kernel(const int* __restrict__ rowptr, const int* __restrict__ rowend,
                              const int* __restrict__ csr_src, const float* __restrict__ rinv,
                              const u8* __restrict__ z28, const float* __restrict__ y2,
                              const float* __restrict__ Wc, const float* __restrict__ bc,
                              float* __restrict__ out) {
    __shared__ float sW[128];
    int t = threadIdx.x;
    if (t < 128) sW[t] = Wc[t];
    __syncthreads();
    int node = blockIdx.x * 16 + (t >> 4);
    int lane = t & 15;
    if (node >= N_NODES) return;
    int beg = rowptr[node];
    int end = rowend[node];
    const u8* zl = z28 + lane * 8;
    float a[8] = {};
    int p = beg;
    for (; p + 3 < end; p += 4) {
        int s0 = csr_src[p], s1 = csr_src[p + 1], s2 = csr_src[p + 2], s3 = csr_src[p + 3];
        uint2 v0 = *(const uint2*)(zl + (size_t)s0 * 128);
        uint2 v1 = *(const uint2*)(zl + (size_t)s1 * 128);
        uint2 v2 = *(const uint2*)(zl + (size_t)s2 * 128);
        uint2 v3 = *(const uint2*)(zl + (size_t)s3 * 128);
        accum8(a, v0); accum8(a, v1); accum8(a, v2); accum8(a, v3);
    }
    for (; p < end; ++p) {
        uint2 v0 = *(const uint2*)(zl + (size_t)csr_src[p] * 128);
        accum8(a, v0);
    }
    float r = rinv[node];
    float4 ylo = *(const float4*)(y2 + (size_t)node * 128 + lane * 8);
    float4 yhi = *(const float4*)(y2 + (size_t)node * 128 + lane * 8 + 4);
    float yv[8] = { ylo.x, ylo.y, ylo.z, ylo.w, yhi.x, yhi.y, yhi.z, yhi.w };
    float s = 0.f;
    #pragma unroll
    for (int j = 0; j < 8; ++j)
        s += (a[j] * r + yv[j]) * sW[lane * 8 + j];
    #pragma unroll
    for (int off = 8; off; off >>= 1) s += __shfl_xor(s, off, 16);
    if (lane == 0) {
        float z = s + bc[0];
        out[node] = 1.0f / (1.0f + expf(-z));
    }
}

extern "C" void kernel_launch(void* const* d_in, const int* in_sizes, int n_in,
                              void* d_out, int out_size, void* d_ws, size_t ws_size,
                              hipStream_t stream) {
    const float* x   = (const float*)d_in[0];
    const int*   ei  = (const int*)d_in[1];
    const float* Wl0 = (const float*)d_in[2];
    const float* Wr0 = (const float*)d_in[3];
    const float* b0  = (const float*)d_in[4];
    const float* Wl1 = (const float*)d_in[5];
    const float* Wr1 = (const float*)d_in[6];
    const float* b1  = (const float*)d_in[7];
    const float* Wl2 = (const float*)d_in[8];
    const float* Wr2 = (const float*)d_in[9];
    const float* b2  = (const float*)d_in[10];
    const float* Wc  = (const float*)d_in[11];
    const float* bc  = (const float*)d_in[12];
    float* out = (float*)d_out;

    const int* src = ei;
    const int* dst = ei + N_EDGES;

    // ---- workspace layout ----
    int*   MT     = (int*)d_ws;                    // MT_PAD
    int*   MTs    = MT + MT_PAD;                   // MT_PAD
    int*   bsums  = MTs + MT_PAD;                  // 1024
    u32*   csrtmp = (u32*)(bsums + 1024);          // N_EDGES
    int*   csr    = (int*)(csrtmp + N_EDGES);      // N_EDGES
    int*   rowptr = csr + N_EDGES;                 // N_PAD
    int*   rowend = rowptr + N_PAD;                // N_PAD
    float* rinv   = (float*)(rowend + N_PAD);      // N_PAD
    u16*   xb     = (u16*)(rinv + N_PAD);          // N_PAD*256 bf16
    u16*   wb     = xb + (size_t)N_PAD * 256;      // weights
    u16*   bufA   = wb + 327680;                   // agg (bf16)
    u16*   bufB   = bufA + (size_t)N_PAD * 256;    // h1 / y2(f32,128)
    u16*   bufC   = bufB + (size_t)N_PAD * 256;    // h2
    u8*    x8     = (u8*)(bufC + (size_t)N_PAD * 256);  // N_PAD*256 fp8
    u8*    h18    = x8 + (size_t)N_PAD * 256;           // N_PAD*256 fp8
    u8*    z28    = h18 + (size_t)N_PAD * 256;          // N_PAD*128 fp8

    u16* wl0 = wb;
    u16* wr0 = wl0 + 65536;
    u16* wl1 = wr0 + 65536;
    u16* wr1 = wl1 + 65536;
    u16* wl2 = wr1 + 65536;
    u16* wr2 = wl2 + 32768;

    // ---- conversions ----
    cvt_kernel<<<(N_NODES * 64 + 255) / 256, 256, 0, stream>>>(x, xb, x8, N_NODES * 64);
    cvtw_kernel<<<320, 256, 0, stream>>>(Wl0, Wr0, Wl1, Wr1, Wl2, Wr2,
                                         wl0, wr0, wl1, wr1, wl2, wr2);

    // ---- CSR build ----
    const int scan_blocks = (MT_N + 255) / 256;    // 783
    p1_hist<<<NC, 256, 0, stream>>>(dst, MT);
    scan1_kernel<<<scan_blocks, 256, 0, stream>>>(MT, MTs, bsums, MT_N);
    scan_carry_kernel<<<1, 256, 0, stream>>>(bsums, scan_blocks);
    scan3_kernel<<<scan_blocks, 256, 0, stream>>>(MTs, bsums, MT_N);
    p2_partition<<<NC, 256, 0, stream>>>(src, dst, MTs, csrtmp);
    p3_csr<<<NB, 256, 0, stream>>>(MTs, csrtmp, csr, rowptr, rowend, rinv);

    const int Mblocks = (N_NODES + 127) / 128;     // 782
    dim3 g01(Mblocks, 2);
    dim3 g2(Mblocks, 2);
    const int agg_blocks = (N_NODES + 15) / 16;    // 6250

    // ---- layer 0 ----
    agg_kernel<<<agg_blocks, 256, 0, stream>>>(rowptr, rowend, csr, rinv, x8, bufA);
    sage_gemm<0><<<g01, 256, 0, stream>>>(bufA, xb, wl0, wr0, b0, bufB, nullptr, h18, 256, 1);

    // ---- layer 1 ----
    agg_kernel<<<agg_blocks, 256, 0, stream>>>(rowptr, rowend, csr, rinv, h18, bufA);
    sage_gemm<0><<<g01, 256, 0, stream>>>(bufA, bufB, wl1, wr1, b1, bufC, nullptr, nullptr, 256, 1);

    // ---- layer 2, projection-first (agg is linear), one dispatch ----
    // y=0: z2 = h2 @ Wl2^T -> fp8 z28 ; y=1: y2 = h2 @ Wr2^T + b2 -> f32 bufB
    sage_gemm<1><<<g2, 256, 0, stream>>>(bufC, nullptr, wl2, wr2, b2, nullptr, bufB, z28, 128, 0);
    // h3 = agg(z2)*rinv + y2, fused with classifier
    aggcls_kernel<<<agg_blocks, 256, 0, stream>>>(rowptr, rowend, csr, rinv,
                                                  z28, (const float*)bufB, Wc, bc, out);
}

// Round 10
// 421.909 us; speedup vs baseline: 41.8078x; 1.0319x over previous
//
#include <hip/hip_runtime.h>
#include <math.h>

#define N_NODES 100000
#define N_PAD   100352
#define N_EDGES 1600000
#define DIN 256

// CSR bucket-partition parameters
#define NB 782        // buckets of 128 dst nodes
#define NC 256        // edge chunks
#define CHUNK 6250    // N_EDGES / NC exactly
#define MT_N (NB * NC)
#define MT_PAD 200448

typedef unsigned short u16;
typedef unsigned char u8;
typedef unsigned int u32;
typedef __attribute__((ext_vector_type(8))) short bf16x8;
typedef __attribute__((ext_vector_type(8))) unsigned short us8;
typedef __attribute__((ext_vector_type(4))) float f32x4;
typedef __attribute__((ext_vector_type(2))) float f32x2;

__device__ __forceinline__ float b2f(u16 u) {
    union { unsigned int i; float f; } c; c.i = ((unsigned int)u) << 16; return c.f;
}
__device__ __forceinline__ u16 f2b(float f) {
    union { float f; unsigned int i; } c; c.f = f;
    unsigned int x = c.i;
    return (u16)((x + 0x7fffu + ((x >> 16) & 1u)) >> 16);   // RNE
}
// hardware fp8 e4m3 (OCP on gfx950) encode/decode — both sides HW, so consistent
__device__ __forceinline__ u8 f32_to_fp8(float v) {
    return (u8)(__builtin_amdgcn_cvt_pk_fp8_f32(v, 0.0f, 0, false) & 0xff);
}
__device__ __forceinline__ void accum16(float* a, uint4 v) {  // 16 fp8 -> += 16 f32
    unsigned int w[4] = { v.x, v.y, v.z, v.w };
    #pragma unroll
    for (int q = 0; q < 4; ++q) {
        f32x2 lo = __builtin_amdgcn_cvt_pk_f32_fp8(w[q], false);
        f32x2 hi = __builtin_amdgcn_cvt_pk_f32_fp8(w[q], true);
        a[q * 4 + 0] += lo[0]; a[q * 4 + 1] += lo[1];
        a[q * 4 + 2] += hi[0]; a[q * 4 + 3] += hi[1];
    }
}
__device__ __forceinline__ void accum8(float* a, uint2 v) {   // 8 fp8 -> += 8 f32
    unsigned int w[2] = { v.x, v.y };
    #pragma unroll
    for (int q = 0; q < 2; ++q) {
        f32x2 lo = __builtin_amdgcn_cvt_pk_f32_fp8(w[q], false);
        f32x2 hi = __builtin_amdgcn_cvt_pk_f32_fp8(w[q], true);
        a[q * 4 + 0] += lo[0]; a[q * 4 + 1] += lo[1];
        a[q * 4 + 2] += hi[0]; a[q * 4 + 3] += hi[1];
    }
}

// async global->LDS, 16B per lane; lds base must be wave-uniform
__device__ __forceinline__ void gload_lds16(const u16* g, u16* lds_base) {
    __builtin_amdgcn_global_load_lds(
        (const __attribute__((address_space(1))) void*)g,
        (__attribute__((address_space(3))) void*)lds_base, 16, 0, 0);
}

// m204 bijective XCD-chunk swizzle: contiguous u-ranges land on one XCD,
// so u and u+1 (the two col-blocks of a row-block) share that XCD's L2.
__device__ __forceinline__ u32 xcd_chunk(u32 orig, u32 nwg) {
    u32 q = nwg >> 3, r = nwg & 7;
    u32 xcd = orig & 7, idx = orig >> 3;
    u32 base = (xcd < r) ? xcd * (q + 1) : r * (q + 1) + (xcd - r) * q;
    return base + idx;
}

// ---------------- f32 -> bf16 + fp8 conversion (x) ----------------
__global__ void cvt_kernel(const float* __restrict__ in, u16* __restrict__ outb,
                           u8* __restrict__ out8, int n4) {
    int i = blockIdx.x * blockDim.x + threadIdx.x;
    if (i < n4) {
        float4 v = ((const float4*)in)[i];
        ushort4 o;
        o.x = f2b(v.x); o.y = f2b(v.y); o.z = f2b(v.z); o.w = f2b(v.w);
        ((ushort4*)outb)[i] = o;
        u32 r = __builtin_amdgcn_cvt_pk_fp8_f32(v.x, v.y, 0, false);
        r = __builtin_amdgcn_cvt_pk_fp8_f32(v.z, v.w, r, true);
        ((u32*)out8)[i] = r;
    }
}

// all 6 weight matrices in one launch
__global__ void cvtw_kernel(const float* __restrict__ Wl0, const float* __restrict__ Wr0,
                            const float* __restrict__ Wl1, const float* __restrict__ Wr1,
                            const float* __restrict__ Wl2, const float* __restrict__ Wr2,
                            u16* __restrict__ wl0, u16* __restrict__ wr0,
                            u16* __restrict__ wl1, u16* __restrict__ wr1,
                            u16* __restrict__ wl2, u16* __restrict__ wr2) {
    int b = blockIdx.x;
    const float* s; u16* d; int i;
    if (b < 64)       { s = Wl0; d = wl0; i = b * 256 + threadIdx.x; }
    else if (b < 128) { s = Wr0; d = wr0; i = (b - 64) * 256 + threadIdx.x; }
    else if (b < 192) { s = Wl1; d = wl1; i = (b - 128) * 256 + threadIdx.x; }
    else if (b < 256) { s = Wr1; d = wr1; i = (b - 192) * 256 + threadIdx.x; }
    else if (b < 288) { s = Wl2; d = wl2; i = (b - 256) * 256 + threadIdx.x; }
    else              { s = Wr2; d = wr2; i = (b - 288) * 256 + threadIdx.x; }
    float4 v = ((const float4*)s)[i];
    ushort4 o;
    o.x = f2b(v.x); o.y = f2b(v.y); o.z = f2b(v.z); o.w = f2b(v.w);
    ((ushort4*)d)[i] = o;
}

// ---------------- CSR build: atomic-free bucket partition ----------------
__launch_bounds__(256)
__global__ void p1_hist(const int* __restrict__ dst, int* __restrict__ MT) {
    __shared__ int bins[NB];
    const int c = blockIdx.x, tid = threadIdx.x;
    for (int b = tid; b < NB; b += 256) bins[b] = 0;
    __syncthreads();
    const int e0 = c * CHUNK;
    for (int e = e0 + tid; e < e0 + CHUNK; e += 256)
        atomicAdd(&bins[dst[e] >> 7], 1);
    __syncthreads();
    for (int b = tid; b < NB; b += 256) MT[b * NC + c] = bins[b];
}

__global__ void scan1_kernel(const int* __restrict__ in, int* __restrict__ excl,
                             int* __restrict__ blocksums, int n) {
    __shared__ int s[256];
    int tid = threadIdx.x;
    int i = blockIdx.x * 256 + tid;
    int v = (i < n) ? in[i] : 0;
    s[tid] = v;
    __syncthreads();
    for (int off = 1; off < 256; off <<= 1) {
        int t = (tid >= off) ? s[tid - off] : 0;
        __syncthreads();
        s[tid] += t;
        __syncthreads();
    }
    if (i < n) excl[i] = s[tid] - v;
    if (tid == 255) blocksums[blockIdx.x] = s[255];
}

__global__ void scan_carry_kernel(int* __restrict__ bsums, int nb) {
    __shared__ int s[256];
    int tid = threadIdx.x;
    int carry = 0;
    for (int base = 0; base < nb; base += 256) {
        int i = base + tid;
        int v = (i < nb) ? bsums[i] : 0;
        s[tid] = v;
        __syncthreads();
        for (int off = 1; off < 256; off <<= 1) {
            int t = (tid >= off) ? s[tid - off] : 0;
            __syncthreads();
            s[tid] += t;
            __syncthreads();
        }
        int incl = s[tid];
        int tot = s[255];
        if (i < nb) bsums[i] = incl - v + carry;
        carry += tot;
        __syncthreads();
    }
}

__global__ void scan3_kernel(int* __restrict__ excl, const int* __restrict__ blocksums, int n) {
    int i = blockIdx.x * 256 + threadIdx.x;
    if (i < n) excl[i] += blocksums[blockIdx.x];
}

__launch_bounds__(256)
__global__ void p2_partition(const int* __restrict__ src, const int* __restrict__ dst,
                             const int* __restrict__ scanMT, u32* __restrict__ csr_tmp) {
    __shared__ int cur[NB];
    const int c = blockIdx.x, tid = threadIdx.x;
    for (int b = tid; b < NB; b += 256) cur[b] = scanMT[b * NC + c];
    __syncthreads();
    const int e0 = c * CHUNK;
    for (int e = e0 + tid; e < e0 + CHUNK; e += 256) {
        int d = dst[e];
        int pos = atomicAdd(&cur[d >> 7], 1);   // LDS atomic
        csr_tmp[pos] = ((u32)(d & 127) << 25) | (u32)src[e];
    }
}

__launch_bounds__(256)
__global__ void p3_csr(const int* __restrict__ scanMT, const u32* __restrict__ csr_tmp,
                       int* __restrict__ csr, int* __restrict__ rowptr,
                       int* __restrict__ rowend, float* __restrict__ rinv) {
    __shared__ int cnt[128];
    __shared__ int excl[128];
    __shared__ int cur[128];
    const int b = blockIdx.x, tid = threadIdx.x;
    const int beg = scanMT[b * NC];
    const int end = (b == NB - 1) ? N_EDGES : scanMT[(b + 1) * NC];
    if (tid < 128) cnt[tid] = 0;
    __syncthreads();
    for (int e = beg + tid; e < end; e += 256)
        atomicAdd(&cnt[csr_tmp[e] >> 25], 1);
    __syncthreads();
    if (tid == 0) {
        int run = 0;
        for (int i = 0; i < 128; ++i) { excl[i] = run; run += cnt[i]; }
    }
    __syncthreads();
    if (tid < 128) cur[tid] = beg + excl[tid];
    __syncthreads();
    for (int e = beg + tid; e < end; e += 256) {
        u32 v = csr_tmp[e];
        int pos = atomicAdd(&cur[v >> 25], 1);  // LDS atomic
        csr[pos] = (int)(v & 0x1FFFFFFu);
    }
    if (tid < 128) {
        int node = b * 128 + tid;
        if (node < N_NODES) {
            int rp = beg + excl[tid];
            rowptr[node] = rp;
            rowend[node] = rp + cnt[tid];
            rinv[node]   = 1.0f / (float)max(cnt[tid], 1);
        }
    }
}

// ---------------- gather aggregation: fp8 rows (256B), 16 lanes/node ----------------
__launch_bounds__(256)
__global__ void agg_kernel(const int* __restrict__ rowptr, const int* __restrict__ rowend,
                           const int* __restrict__ csr_src, const float* __restrict__ rinv,
                           const u8* __restrict__ h8, u16* __restrict__ agg) {
    int node = blockIdx.x * 16 + (threadIdx.x >> 4);
    int lane = threadIdx.x & 15;
    if (node >= N_NODES) return;
    int beg = rowptr[node];
    int end = rowend[node];
    const u8* hl = h8 + lane * 16;
    float a[16] = {};
    int p = beg;
    for (; p + 3 < end; p += 4) {
        int s0 = csr_src[p], s1 = csr_src[p + 1], s2 = csr_src[p + 2], s3 = csr_src[p + 3];
        uint4 v0 = *(const uint4*)(hl + (size_t)s0 * 256);
        uint4 v1 = *(const uint4*)(hl + (size_t)s1 * 256);
        uint4 v2 = *(const uint4*)(hl + (size_t)s2 * 256);
        uint4 v3 = *(const uint4*)(hl + (size_t)s3 * 256);
        accum16(a, v0); accum16(a, v1); accum16(a, v2); accum16(a, v3);
    }
    for (; p < end; ++p) {
        uint4 v0 = *(const uint4*)(hl + (size_t)csr_src[p] * 256);
        accum16(a, v0);
    }
    float r = rinv[node];
    us8 o0, o1;
    #pragma unroll
    for (int j = 0; j < 8; ++j) { o0[j] = f2b(a[j] * r); o1[j] = f2b(a[8 + j] * r); }
    u16* d = agg + (size_t)node * DIN + lane * 16;
    *(us8*)d = o0;
    *(us8*)(d + 8) = o1;
}

// ---------------- MFMA GEMM: counted-vmcnt pipeline (T4), raw barriers ----------------
// LDS tiles linear [128][32] u16. Both-sides XOR swizzle, blk = lg ^ ((row>>1)&3):
//   even/odd row classes each spread over 4 bank-quads -> worst 2-way (free, m136).
// 1D grid of 1564, u = xcd_chunk(blockIdx.x): col = u&1, rowblk = u>>1 so both
// col-blocks of a row-block run adjacently on one XCD (A-tile L2 reuse).
// MODE 0: DUAL K=512, out = act([A0|A1]@[B0w|B1w]^T + bias) -> bf16 out0 (+ fp8 out8)
// MODE 1: K=256: col==0: A0@B0w^T -> fp8 out8 (no bias); col==1: A0@B1w^T+bias -> f32 out1
template <int MODE>
__launch_bounds__(256)
__global__ void sage_gemm(const u16* __restrict__ A0, const u16* __restrict__ A1,
                          const u16* __restrict__ B0w, const u16* __restrict__ B1w,
                          const float* __restrict__ bias, void* __restrict__ out0,
                          void* __restrict__ out1, u8* __restrict__ out8,
                          int dout, int do_relu) {
    __shared__ u16 sA[2][128 * 32];
    __shared__ u16 sB[2][128 * 32];

    const u32 u    = xcd_chunk(blockIdx.x, gridDim.x);
    const int csel = u & 1;
    const int row0 = (int)(u >> 1) * 128;
    const int col0 = (MODE == 0) ? csel * 128 : 0;
    const int t    = threadIdx.x;
    const int w    = t >> 6, lane = t & 63;
    const int wr   = w >> 1, wc = w & 1;
    const int lr   = lane & 15, lg = lane >> 4;
    const int srow = lane >> 2;                       // 0..15
    const int sblk = (lane & 3) ^ ((lane >> 3) & 3);  // (srow>>1)&3 swizzle
    const u16* Bsel = csel ? B1w : B0w;

    f32x4 acc[4][4] = {};
    const int NT = (MODE == 0) ? 16 : 8;

    auto stage = [&](int buf, int tk) {
        const int kt = tk * 32;
        const u16* Asrc = (MODE == 0 && kt >= 256) ? A1 : A0;
        const u16* Bsrc = (MODE == 0) ? ((kt >= 256) ? B1w : B0w) : Bsel;
        const int  kb   = (MODE == 0 && kt >= 256) ? kt - 256 : kt;
        #pragma unroll
        for (int i = 0; i < 2; ++i) {
            int row = w * 32 + i * 16 + srow;
            gload_lds16(Asrc + (size_t)(row0 + row) * DIN + kb + sblk * 8,
                        &sA[buf][w * 1024 + i * 512]);
            gload_lds16(Bsrc + (size_t)(col0 + row) * DIN + kb + sblk * 8,
                        &sB[buf][w * 1024 + i * 512]);
        }
    };

    stage(0, 0);
    stage(1, 1);                 // 8 loads in flight
    for (int tk = 0; tk < NT; ++tk) {
        const int cur = tk & 1;
        // wait only for buf[cur]'s 4 loads; keep the other stage's 4 in flight
        if (tk + 1 < NT) asm volatile("s_waitcnt vmcnt(4)" ::: "memory");
        else             asm volatile("s_waitcnt vmcnt(0)" ::: "memory");
        __builtin_amdgcn_sched_barrier(0);
        __builtin_amdgcn_s_barrier();         // all waves: buf[cur] complete

        bf16x8 af[4], bfr[4];
        #pragma unroll
        for (int m = 0; m < 4; ++m) {
            int row = wr * 64 + m * 16 + lr;
            af[m] = *(const bf16x8*)&sA[cur][row * 32 + 8 * (lg ^ ((lr >> 1) & 3))];
        }
        #pragma unroll
        for (int n = 0; n < 4; ++n) {
            int row = wc * 64 + n * 16 + lr;
            bfr[n] = *(const bf16x8*)&sB[cur][row * 32 + 8 * (lg ^ ((lr >> 1) & 3))];
        }
        #pragma unroll
        for (int m = 0; m < 4; ++m)
            #pragma unroll
            for (int n = 0; n < 4; ++n)
                acc[m][n] = __builtin_amdgcn_mfma_f32_16x16x32_bf16(af[m], bfr[n], acc[m][n], 0, 0, 0);

        // drain this wave's ds_reads, then barrier so buf[cur] can be restaged
        asm volatile("s_waitcnt lgkmcnt(0)" ::: "memory");
        __builtin_amdgcn_sched_barrier(0);
        __builtin_amdgcn_s_barrier();
        if (tk + 2 < NT) stage(cur, tk + 2);
    }

    const bool f32out = (MODE == 1) && (csel == 1);
    #pragma unroll
    for (int m = 0; m < 4; ++m) {
        int row = row0 + wr * 64 + m * 16 + lg * 4;
        #pragma unroll
        for (int n = 0; n < 4; ++n) {
            int col = col0 + wc * 64 + n * 16 + lr;
            #pragma unroll
            for (int r = 0; r < 4; ++r) {
                float v = acc[m][n][r];
                if (MODE == 0) {
                    v += bias[col];
                    if (do_relu) v = fmaxf(v, 0.0f);
                    ((u16*)out0)[(size_t)(row + r) * dout + col] = f2b(v);
                    if (out8) out8[(size_t)(row + r) * dout + col] = f32_to_fp8(v);
                } else if (f32out) {
                    v += bias[col];
                    ((float*)out1)[(size_t)(row + r) * dout + col] = v;
                } else {
                    out8[(size_t)(row + r) * dout + col] = f32_to_fp8(v);
                }
            }
        }
    }
}

// ---------------- fused layer-2 agg + classifier: fp8 z2 rows (128B) ----------------
__launch_bounds__(256)
__global__ void aggcls_kernel(const int* __restrict__ rowptr, const int* __restrict__ rowend,
                              const int* __restrict__ csr_src, const float* __restrict__ rinv,
                              const u8* __restrict__ z28, const float* __restrict__ y2,
                              const float* __restrict__ Wc, const float* __restrict__ bc,
                              float* __restrict__ out) {
    __shared__ float sW[128];
    int t = threadIdx.x;
    if (t < 128) sW[t] = Wc[t];
    __syncthreads();
    int node = blockIdx.x * 16 + (t >> 4);
    int lane = t & 15;
    if (node >= N_NODES) return;
    int beg = rowptr[node];
    int end = rowend[node];
    const u8* zl = z28 + lane * 8;
    float a[8] = {};
    int p = beg;
    for (; p + 3 < end; p += 4) {
        int s0 = csr_src[p], s1 = csr_src[p + 1], s2 = csr_src[p + 2], s3 = csr_src[p + 3];
        uint2 v0 = *(const uint2*)(zl + (size_t)s0 * 128);
        uint2 v1 = *(const uint2*)(zl + (size_t)s1 * 128);
        uint2 v2 = *(const uint2*)(zl + (size_t)s2 * 128);
        uint2 v3 = *(const uint2*)(zl + (size_t)s3 * 128);
        accum8(a, v0); accum8(a, v1); accum8(a, v2); accum8(a, v3);
    }
    for (; p < end; ++p) {
        uint2 v0 = *(const uint2*)(zl + (size_t)csr_src[p] * 128);
        accum8(a, v0);
    }
    float r = rinv[node];
    float4 ylo = *(const float4*)(y2 + (size_t)node * 128 + lane * 8);
    float4 yhi = *(const float4*)(y2 + (size_t)node * 128 + lane * 8 + 4);
    float yv[8] = { ylo.x, ylo.y, ylo.z, ylo.w, yhi.x, yhi.y, yhi.z, yhi.w };
    float s = 0.f;
    #pragma unroll
    for (int j = 0; j < 8; ++j)
        s += (a[j] * r + yv[j]) * sW[lane * 8 + j];
    #pragma unroll
    for (int off = 8; off; off >>= 1) s += __shfl_xor(s, off, 16);
    if (lane == 0) {
        float z = s + bc[0];
        out[node] = 1.0f / (1.0f + expf(-z));
    }
}

extern "C" void kernel_launch(void* const* d_in, const int* in_sizes, int n_in,
                              void* d_out, int out_size, void* d_ws, size_t ws_size,
                              hipStream_t stream) {
    const float* x   = (const float*)d_in[0];
    const int*   ei  = (const int*)d_in[1];
    const float* Wl0 = (const float*)d_in[2];
    const float* Wr0 = (const float*)d_in[3];
    const float* b0  = (const float*)d_in[4];
    const float* Wl1 = (const float*)d_in[5];
    const float* Wr1 = (const float*)d_in[6];
    const float* b1  = (const float*)d_in[7];
    const float* Wl2 = (const float*)d_in[8];
    const float* Wr2 = (const float*)d_in[9];
    const float* b2  = (const float*)d_in[10];
    const float* Wc  = (const float*)d_in[11];
    const float* bc  = (const float*)d_in[12];
    float* out = (float*)d_out;

    const int* src = ei;
    const int* dst = ei + N_EDGES;

    // ---- workspace layout ----
    int*   MT     = (int*)d_ws;                    // MT_PAD
    int*   MTs    = MT + MT_PAD;                   // MT_PAD
    int*   bsums  = MTs + MT_PAD;                  // 1024
    u32*   csrtmp = (u32*)(bsums + 1024);          // N_EDGES
    int*   csr    = (int*)(csrtmp + N_EDGES);      // N_EDGES
    int*   rowptr = csr + N_EDGES;                 // N_PAD
    int*   rowend = rowptr + N_PAD;                // N_PAD
    float* rinv   = (float*)(rowend + N_PAD);      // N_PAD
    u16*   xb     = (u16*)(rinv + N_PAD);          // N_PAD*256 bf16
    u16*   wb     = xb + (size_t)N_PAD * 256;      // weights
    u16*   bufA   = wb + 327680;                   // agg (bf16)
    u16*   bufB   = bufA + (size_t)N_PAD * 256;    // h1 / y2(f32,128)
    u16*   bufC   = bufB + (size_t)N_PAD * 256;    // h2
    u8*    x8     = (u8*)(bufC + (size_t)N_PAD * 256);  // N_PAD*256 fp8
    u8*    h18    = x8 + (size_t)N_PAD * 256;           // N_PAD*256 fp8
    u8*    z28    = h18 + (size_t)N_PAD * 256;          // N_PAD*128 fp8

    u16* wl0 = wb;
    u16* wr0 = wl0 + 65536;
    u16* wl1 = wr0 + 65536;
    u16* wr1 = wl1 + 65536;
    u16* wl2 = wr1 + 65536;
    u16* wr2 = wl2 + 32768;

    // ---- conversions ----
    cvt_kernel<<<(N_NODES * 64 + 255) / 256, 256, 0, stream>>>(x, xb, x8, N_NODES * 64);
    cvtw_kernel<<<320, 256, 0, stream>>>(Wl0, Wr0, Wl1, Wr1, Wl2, Wr2,
                                         wl0, wr0, wl1, wr1, wl2, wr2);

    // ---- CSR build ----
    const int scan_blocks = (MT_N + 255) / 256;    // 783
    p1_hist<<<NC, 256, 0, stream>>>(dst, MT);
    scan1_kernel<<<scan_blocks, 256, 0, stream>>>(MT, MTs, bsums, MT_N);
    scan_carry_kernel<<<1, 256, 0, stream>>>(bsums, scan_blocks);
    scan3_kernel<<<scan_blocks, 256, 0, stream>>>(MTs, bsums, MT_N);
    p2_partition<<<NC, 256, 0, stream>>>(src, dst, MTs, csrtmp);
    p3_csr<<<NB, 256, 0, stream>>>(MTs, csrtmp, csr, rowptr, rowend, rinv);

    const int Mblocks = (N_NODES + 127) / 128;     // 782
    const int gemm_blocks = Mblocks * 2;           // 1564 (1D, xcd-chunked)
    const int agg_blocks = (N_NODES + 15) / 16;    // 6250

    // ---- layer 0 ----
    agg_kernel<<<agg_blocks, 256, 0, stream>>>(rowptr, rowend, csr, rinv, x8, bufA);
    sage_gemm<0><<<gemm_blocks, 256, 0, stream>>>(bufA, xb, wl0, wr0, b0, bufB, nullptr, h18, 256, 1);

    // ---- layer 1 ----
    agg_kernel<<<agg_blocks, 256, 0, stream>>>(rowptr, rowend, csr, rinv, h18, bufA);
    sage_gemm<0><<<gemm_blocks, 256, 0, stream>>>(bufA, bufB, wl1, wr1, b1, bufC, nullptr, nullptr, 256, 1);

    // ---- layer 2, projection-first (agg is linear), one dispatch ----
    // col=0: z2 = h2 @ Wl2^T -> fp8 z28 ; col=1: y2 = h2 @ Wr2^T + b2 -> f32 bufB
    sage_gemm<1><<<gemm_blocks, 256, 0, stream>>>(bufC, nullptr, wl2, wr2, b2, nullptr, bufB, z28, 128, 0);
    // h3 = agg(z2)*rinv + y2, fused with classifier
    aggcls_kernel<<<agg_blocks, 256, 0, stream>>>(rowptr, rowend, csr, rinv,
                                                  z28, (const float*)bufB, Wc, bc, out);
}